// Round 6
// baseline (222.668 us; speedup 1.0000x reference)
//
#include <hip/hip_runtime.h>
#include <stdint.h>

// ---------------------------------------------------------------------------
// MultiAttentionHead: B=4 S=1024 E=1024 H=16 D=64, fp32 in/out.
// GEMMs in bf16 MFMA with hi/lo split. Projections: 2 passes C ~= xh*(Wh+Wl).
// Attention: QK = qh*(kh+kl), PV = p*(vh+vl), p bf16, l summed from rounded p.
// Rows s >= len[b] get uniform attention = mean(V) per ref.
// R1: k_proj fused single-staging + XOR bank swizzle (0 conflicts measured).
// R2: k_attn wave-private P, DPP reductions, exp2 folding.
// R3: k_proj 2-pass + BK=64, x-lo split dropped.
// R4: static softmax (no online max), C folded into q, P aliases Q's LDS.
// R5: flash-decoding t-split -- static softmax partials are ADDITIVE, so
//     each (bh, q-tile, t-chunk<=256) block atomicAdds unnormalized O into
//     d_out and l into lacc; k_finalize normalizes in place. Fixes the
//     parallelism/imbalance bottleneck (was ~2.1 unbalanced blocks/CU).
// ---------------------------------------------------------------------------

using u16     = unsigned short;
using short8  = __attribute__((ext_vector_type(8))) short;
using floatx4 = __attribute__((ext_vector_type(4))) float;

#define MFMA(a, b, c) __builtin_amdgcn_mfma_f32_16x16x32_bf16(a, b, c, 0, 0, 0)

__device__ __forceinline__ float bf2f(u16 u) {
  uint32_t t = ((uint32_t)u) << 16; float f; __builtin_memcpy(&f, &t, 4); return f;
}
__device__ __forceinline__ u16 f2bf(float f) {  // round-to-nearest-even
  uint32_t x; __builtin_memcpy(&x, &f, 4);
  x += 0x7FFFu + ((x >> 16) & 1u);
  return (u16)(x >> 16);
}

// DPP rotate within aligned 16-lane rows (pure VALU; no LDS pipe).
template <int CTRL>
__device__ __forceinline__ float dppf(float v) {
  return __int_as_float(__builtin_amdgcn_update_dpp(
      0, __float_as_int(v), CTRL, 0xF, 0xF, true));
}
__device__ __forceinline__ float rowsum16(float v) {  // all-reduce sum, 16 lanes
  v += dppf<0x121>(v);
  v += dppf<0x122>(v);
  v += dppf<0x124>(v);
  v += dppf<0x128>(v);
  return v;
}

// async global->LDS DMA, 16B per lane. LDS dest must be wave-uniform base +
// lane*16 (no per-lane scatter) -- so bank swizzles permute the GLOBAL src.
__device__ __forceinline__ void async_cp16(void* lds, const void* g) {
  __builtin_amdgcn_global_load_lds(
      (__attribute__((address_space(1))) uint32_t*)(uintptr_t)g,
      (__attribute__((address_space(3))) uint32_t*)(uint32_t)(uintptr_t)lds,
      16, 0, 0);
}

// ---------------------------------------------------------------------------
// 0) zero d_out (4M floats) + lacc (64K floats): harness poisons with 0xAA.
// ---------------------------------------------------------------------------
__global__ void k_zero(float* __restrict__ out, float* __restrict__ lacc) {
  int i = blockIdx.x * 256 + threadIdx.x;
  float4 z = {0.f, 0.f, 0.f, 0.f};
  if (i < 1048576) ((float4*)out)[i] = z;
  else if (i < 1048576 + 16384) ((float4*)lacc)[i - 1048576] = z;
}

// ---------------------------------------------------------------------------
// 1) split x (fp32) -> xhi (bf16)
// ---------------------------------------------------------------------------
__global__ void k_split_x(const float* __restrict__ x, u16* __restrict__ xhi) {
  int i = (blockIdx.x * 256 + threadIdx.x) * 4;
  float4 v = *(const float4*)(x + i);
  ushort4 hv;
  hv.x = f2bf(v.x);
  hv.y = f2bf(v.y);
  hv.z = f2bf(v.z);
  hv.w = f2bf(v.w);
  *(ushort4*)(xhi + i) = hv;
}

// ---------------------------------------------------------------------------
// 2) transpose + split weights: W[k][n] fp32 -> WT[n][k] bf16 hi/lo (B^T form)
// ---------------------------------------------------------------------------
__global__ void k_wsplit(const float* __restrict__ w0, const float* __restrict__ w1,
                         const float* __restrict__ w2,
                         u16* __restrict__ o0h, u16* __restrict__ o0l,
                         u16* __restrict__ o1h, u16* __restrict__ o1l,
                         u16* __restrict__ o2h, u16* __restrict__ o2l) {
  __shared__ float t[32][33];
  const int z = blockIdx.z;
  const float* W = z == 0 ? w0 : (z == 1 ? w1 : w2);
  u16* oh = z == 0 ? o0h : (z == 1 ? o1h : o2h);
  u16* ol = z == 0 ? o0l : (z == 1 ? o1l : o2l);
  const int kb = blockIdx.x * 32, nb = blockIdx.y * 32;
  const int tx = threadIdx.x & 31, ty = threadIdx.x >> 5;
  for (int r = ty; r < 32; r += 8) t[r][tx] = W[(kb + r) * 1024 + nb + tx];
  __syncthreads();
  for (int r = ty; r < 32; r += 8) {
    float v = t[tx][r];
    u16 hh = f2bf(v);
    int idx = (nb + r) * 1024 + kb + tx;
    oh[idx] = hh;
    ol[idx] = f2bf(v - bf2f(hh));
  }
}

// ---------------------------------------------------------------------------
// 3) projection GEMM: C[4096][1024] = xh @ (Wh + Wl) + b, 128x128 tile,
//    BK=64. LDS 48 KB: Ah + Bh + Bl [128][64], 8-chunk XOR swizzle.
//    q output (z==0) is pre-scaled by 0.125*log2(e) so k_attn can exp2 raw
//    scores. Output re-split to bf16 hi/lo, layout [B][H][S][D].
// ---------------------------------------------------------------------------
__launch_bounds__(256, 3)
__global__ void k_proj(const u16* __restrict__ xhi,
                       const u16* __restrict__ wqh, const u16* __restrict__ wql,
                       const u16* __restrict__ wkh, const u16* __restrict__ wkl,
                       const u16* __restrict__ wvh, const u16* __restrict__ wvl,
                       const float* __restrict__ bq, const float* __restrict__ bk,
                       const float* __restrict__ bv,
                       u16* __restrict__ qh, u16* __restrict__ ql,
                       u16* __restrict__ kh, u16* __restrict__ kl,
                       u16* __restrict__ vh, u16* __restrict__ vl) {
  __shared__ u16 Sm[24576];  // Ah@0, Bh@8192, Bl@16384 -- each [128][64]
  const int z = blockIdx.z;
  const u16* wh = z == 0 ? wqh : (z == 1 ? wkh : wvh);
  const u16* wl = z == 0 ? wql : (z == 1 ? wkl : wvl);
  const float* bias = z == 0 ? bq : (z == 1 ? bk : bv);
  u16* oh = z == 0 ? qh : (z == 1 ? kh : vh);
  u16* ol = z == 0 ? ql : (z == 1 ? kl : vl);
  const float oscale = (z == 0) ? 0.18033688011112042f : 1.0f;  // 0.125*log2(e)

  const int tid = threadIdx.x, l = tid & 63, w = tid >> 6;
  const int quad = l >> 4, col = l & 15;
  const int m0 = blockIdx.x * 128, n0 = blockIdx.y * 128;
  const int wm = (w & 1) * 64, wn = (w >> 1) * 64;

  const int row0 = tid >> 3, ch = tid & 7;
  const int sc8 = (ch ^ (row0 & 7)) * 8;
  int gofs[4], lofs[4];
#pragma unroll
  for (int p = 0; p < 4; p++) {
    gofs[p] = (row0 + 32 * p) * 1024 + sc8;
    lofs[p] = (tid + p * 256) * 8;
  }

  const u16* Ag  = xhi + m0 * 1024;
  const u16* Bhg = wh + n0 * 1024;
  const u16* Blg = wl + n0 * 1024;

  int ar[2][4], br[2][4];
#pragma unroll
  for (int ks = 0; ks < 2; ks++) {
#pragma unroll
    for (int i = 0; i < 4; i++) {
      int r = wm + i * 16 + col;
      ar[ks][i] = r * 64 + (((ks * 4 + quad) ^ (r & 7)) * 8);
    }
#pragma unroll
    for (int j = 0; j < 4; j++) {
      int r = wn + j * 16 + col;
      br[ks][j] = r * 64 + (((ks * 4 + quad) ^ (r & 7)) * 8);
    }
  }

  floatx4 zero4 = {0.f, 0.f, 0.f, 0.f};
  floatx4 acc[4][4];
#pragma unroll
  for (int i = 0; i < 4; i++)
#pragma unroll
    for (int j = 0; j < 4; j++) acc[i][j] = zero4;

  for (int k0 = 0; k0 < 1024; k0 += 64) {
    __syncthreads();
#pragma unroll
    for (int p = 0; p < 4; p++) async_cp16(Sm + lofs[p], Ag + gofs[p] + k0);
#pragma unroll
    for (int p = 0; p < 4; p++)
      async_cp16(Sm + 8192 + lofs[p], Bhg + gofs[p] + k0);
#pragma unroll
    for (int p = 0; p < 4; p++)
      async_cp16(Sm + 16384 + lofs[p], Blg + gofs[p] + k0);
    __syncthreads();

#pragma unroll
    for (int ks = 0; ks < 2; ks++) {
      short8 fah[4], fbh[4];
#pragma unroll
      for (int i = 0; i < 4; i++) fah[i] = *(const short8*)(Sm + ar[ks][i]);
#pragma unroll
      for (int j = 0; j < 4; j++)
        fbh[j] = *(const short8*)(Sm + 8192 + br[ks][j]);
#pragma unroll
      for (int i = 0; i < 4; i++)
#pragma unroll
        for (int j = 0; j < 4; j++) acc[i][j] = MFMA(fah[i], fbh[j], acc[i][j]);

      short8 fbl[4];
#pragma unroll
      for (int j = 0; j < 4; j++)
        fbl[j] = *(const short8*)(Sm + 16384 + br[ks][j]);
#pragma unroll
      for (int i = 0; i < 4; i++)
#pragma unroll
        for (int j = 0; j < 4; j++) acc[i][j] = MFMA(fah[i], fbl[j], acc[i][j]);
    }
  }

  const bool wlo = (ol != nullptr);
#pragma unroll
  for (int j = 0; j < 4; j++) {
    int n = n0 + wn + j * 16 + col;
    float bb = bias[n];
    int hh = n >> 6, d = n & 63;
#pragma unroll
    for (int i = 0; i < 4; i++) {
      int mbase = m0 + wm + i * 16 + quad * 4;
#pragma unroll
      for (int r = 0; r < 4; r++) {
        int m = mbase + r;
        int bidx = m >> 10, s = m & 1023;
        float v = (acc[i][j][r] + bb) * oscale;
        int idx = ((bidx * 16 + hh) * 1024 + s) * 64 + d;
        u16 vh16 = f2bf(v);
        oh[idx] = vh16;
        if (wlo) ol[idx] = f2bf(v - bf2f(vh16));
      }
    }
  }
}

// ---------------------------------------------------------------------------
// 4) transpose V per (b,h): [S][D] -> [D][S] (hi & lo), LDS-tiled 32x32
// ---------------------------------------------------------------------------
__global__ void k_vt(const u16* __restrict__ vh, const u16* __restrict__ vl,
                     u16* __restrict__ vth, u16* __restrict__ vtl) {
  __shared__ u16 th[32][33], tl[32][33];
  const int bh = blockIdx.z, sb = blockIdx.x * 32, db = blockIdx.y * 32;
  const int tx = threadIdx.x & 31, ty = threadIdx.x >> 5;
  const u16* sh = vh + bh * 65536;
  const u16* sl = vl + bh * 65536;
  for (int r = ty; r < 32; r += 8) {
    th[r][tx] = sh[(sb + r) * 64 + db + tx];
    tl[r][tx] = sl[(sb + r) * 64 + db + tx];
  }
  __syncthreads();
  u16* dh = vth + bh * 65536;
  u16* dl = vtl + bh * 65536;
  for (int r = ty; r < 32; r += 8) {
    dh[(db + r) * 1024 + sb + tx] = th[tx][r];
    dl[(db + r) * 1024 + sb + tx] = tl[tx][r];
  }
}

// ---------------------------------------------------------------------------
// 5) vsum[bh*64+d] = sum_t V[b,h,t,d]  (for uniform-attention rows s>=len)
// ---------------------------------------------------------------------------
__global__ void k_vsum(const u16* __restrict__ vth, const u16* __restrict__ vtl,
                       float* __restrict__ vsum) {
  int row = blockIdx.x * 4 + (threadIdx.x >> 6);
  int l = threadIdx.x & 63;
  const u16* ph = vth + row * 1024;
  const u16* pl = vtl + row * 1024;
  float s = 0.f;
  for (int i = 0; i < 16; i++) {
    int t = i * 64 + l;
    s += bf2f(ph[t]) + bf2f(pl[t]);
  }
  for (int m = 32; m >= 1; m >>= 1) s += __shfl_xor(s, m, 64);
  if (l == 0) vsum[row] = s;
}

// ---------------------------------------------------------------------------
// Swizzled 64x64 bf16 tile stage (global -> LDS via DMA).
// ---------------------------------------------------------------------------
__device__ __forceinline__ void stage64(u16* lds, const u16* g, int row_stride,
                                        int tid) {
#pragma unroll
  for (int p = 0; p < 2; p++) {
    int slot = (p * 256 + tid) * 8;  // element index; *2 = bytes
    int row = slot >> 6;
    int gp = (slot >> 3) & 7;
    int gl = gp ^ (row & 7);
    async_cp16(lds + slot, g + row * row_stride + gl * 8);
  }
}

// ---------------------------------------------------------------------------
// 6) flash attention PARTIAL, static softmax. Grid (bh, q-tile, t-chunk of
//    256). Static softmax partials are additive across t-chunks, so each
//    block atomicAdds unnormalized O (fp32) into d_out (whose layout matches)
//    and per-row l into lacc. <=4 t-iters/block -> balanced; ~1350 valid
//    blocks vs ~550. LDS 40960 B. Finalize kernel normalizes.
// ---------------------------------------------------------------------------
__launch_bounds__(256)
__global__ void k_attn_partial(const u16* __restrict__ qh_g,
                               const u16* __restrict__ kh_g,
                               const u16* __restrict__ kl_g,
                               const u16* __restrict__ vth_g,
                               const u16* __restrict__ vtl_g,
                               const int* __restrict__ elen,
                               float* __restrict__ oacc,   // == d_out layout
                               float* __restrict__ lacc) { // [B][S][H]
  __shared__ u16 QP[4096];              // [64][64] swizzled: Q, then P (aliased)
  __shared__ u16 Kh[4096], Kl[4096];    // [64 t][64 d] swizzled
  __shared__ u16 VTh[4096], VTl[4096];  // [64 d][64 t] swizzled
  const int tid = threadIdx.x, l = tid & 63, w = tid >> 6;
  const int quad = l >> 4, col = l & 15;
  const int bh = blockIdx.x, b = bh >> 4, h = bh & 15;
  const int q0 = blockIdx.y * 64;
  const int len = elen[b];
  const int tbeg = blockIdx.z * 256;

  if (q0 >= len || tbeg >= len) return;  // finalize covers invalid rows
  const int tend = min(len, tbeg + 256);

  stage64(QP, qh_g + (bh * 1024 + q0) * 64, 64, tid);
  __syncthreads();

  short8 qf[2];  // persistent Q fragments (A-layout: m=lane&15, k=quad*8+j)
  {
    int qrow = w * 16 + col;
#pragma unroll
    for (int ks = 0; ks < 2; ks++)
      qf[ks] = *(const short8*)(QP + qrow * 64 +
                                (((ks * 4 + quad) ^ (qrow & 7)) * 8));
  }

  // fragment offsets (same swizzle for K and VT tiles)
  int kvo[2][4];
#pragma unroll
  for (int ks = 0; ks < 2; ks++)
#pragma unroll
    for (int j = 0; j < 4; j++) {
      int n = j * 16 + col;
      kvo[ks][j] = n * 64 + (((ks * 4 + quad) ^ (n & 7)) * 8);
    }
  int p_rd[2];
#pragma unroll
  for (int ks = 0; ks < 2; ks++) {
    int row = w * 16 + col;
    p_rd[ks] = row * 64 + (((ks * 4 + quad) ^ (row & 7)) * 8);
  }
  int p_wr[4][4];
#pragma unroll
  for (int r = 0; r < 4; r++) {
    int row = w * 16 + quad * 4 + r;
#pragma unroll
    for (int j = 0; j < 4; j++) {
      int cj = j * 2 + (col >> 3);
      p_wr[r][j] = row * 64 + ((cj ^ (row & 7)) * 8) + (col & 7);
    }
  }

  floatx4 zero4 = {0.f, 0.f, 0.f, 0.f};
  floatx4 O[4];
  float lp[4];  // per-thread partial l (reduced after the loop)
#pragma unroll
  for (int j = 0; j < 4; j++) O[j] = zero4;
#pragma unroll
  for (int r = 0; r < 4; r++) lp[r] = 0.f;

  for (int t0 = tbeg; t0 < tend; t0 += 64) {
    __syncthreads();  // prev QK/PV reads done before K/VT overwrite
    stage64(Kh, kh_g + (bh * 1024 + t0) * 64, 64, tid);
    stage64(Kl, kl_g + (bh * 1024 + t0) * 64, 64, tid);
    stage64(VTh, vth_g + bh * 65536 + t0, 1024, tid);
    stage64(VTl, vtl_g + bh * 65536 + t0, 1024, tid);
    __syncthreads();  // DMA drained

    // ---- raw scores = Q K^T (qh * (kh + kl)); q carries 0.125*log2e ----
    floatx4 sc[4];
#pragma unroll
    for (int j = 0; j < 4; j++) sc[j] = zero4;
#pragma unroll
    for (int ks = 0; ks < 2; ks++) {
#pragma unroll
      for (int j = 0; j < 4; j++) {
        short8 kbh = *(const short8*)(Kh + kvo[ks][j]);
        short8 kbl = *(const short8*)(Kl + kvo[ks][j]);
        sc[j] = MFMA(qf[ks], kbh, sc[j]);
        sc[j] = MFMA(qf[ks], kbl, sc[j]);
      }
    }

    if (t0 + 64 > len) {  // wave-uniform: only the last partial tile masks
#pragma unroll
      for (int j = 0; j < 4; j++) {
        bool inv = (t0 + j * 16 + col) >= len;
#pragma unroll
        for (int r = 0; r < 4; r++)
          if (inv) sc[j][r] = -3e38f;  // exp2 -> 0
      }
    }

    // ---- static softmax weights: p = exp2(score), bf16-rounded ----
#pragma unroll
    for (int r = 0; r < 4; r++) {
#pragma unroll
      for (int j = 0; j < 4; j++) {
        float e = __builtin_exp2f(sc[j][r]);
        u16 pe = f2bf(e);
        QP[p_wr[r][j]] = pe;   // wave-private rows; no barrier needed
        lp[r] += bf2f(pe);     // l sums the weights actually used
      }
    }

    // ---- O += P * (vh + vl) ----
#pragma unroll
    for (int ks = 0; ks < 2; ks++) {
      short8 pa = *(const short8*)(QP + p_rd[ks]);
#pragma unroll
      for (int j = 0; j < 4; j++) {
        short8 vbh = *(const short8*)(VTh + kvo[ks][j]);
        short8 vbl = *(const short8*)(VTl + kvo[ks][j]);
        O[j] = MFMA(pa, vbh, O[j]);
        O[j] = MFMA(pa, vbl, O[j]);
      }
    }
  }

  // ---- epilogue: atomic-accumulate partial l and O ----
  float l_r[4];
#pragma unroll
  for (int r = 0; r < 4; r++) l_r[r] = rowsum16(lp[r]);
#pragma unroll
  for (int r = 0; r < 4; r++) {
    int s = q0 + w * 16 + quad * 4 + r;
    if (s < len) {
      if (col == 0) unsafeAtomicAdd(lacc + (b * 1024 + s) * 16 + h, l_r[r]);
      float* obase = oacc + (b * 1024 + s) * 1024 + h * 64 + col;
#pragma unroll
      for (int j = 0; j < 4; j++)
        unsafeAtomicAdd(obase + j * 16, O[j][r]);
    }
  }
}

// ---------------------------------------------------------------------------
// 7) finalize: out = valid ? Oacc/l : vsum/1024, in place over d_out.
// ---------------------------------------------------------------------------
__global__ void k_finalize(float* __restrict__ out, const float* __restrict__ lacc,
                           const float* __restrict__ vsum,
                           const int* __restrict__ elen) {
  int idx = (blockIdx.x * 256 + threadIdx.x) * 4;  // over 4M floats
  int d = idx & 63, h = (idx >> 6) & 15, s = (idx >> 10) & 1023, b = idx >> 20;
  float4 v;
  if (s < elen[b]) {
    v = *(float4*)(out + idx);
    float inv = 1.0f / lacc[(b * 1024 + s) * 16 + h];
    v.x *= inv; v.y *= inv; v.z *= inv; v.w *= inv;
  } else {
    const float* vs = vsum + (b * 16 + h) * 64 + d;
    const float u = 1.0f / 1024.0f;
    v.x = vs[0] * u; v.y = vs[1] * u; v.z = vs[2] * u; v.w = vs[3] * u;
  }
  *(float4*)(out + idx) = v;
}

// ---------------------------------------------------------------------------
// launch
// ---------------------------------------------------------------------------
extern "C" void kernel_launch(void* const* d_in, const int* in_sizes, int n_in,
                              void* d_out, int out_size, void* d_ws, size_t ws_size,
                              hipStream_t stream) {
  (void)in_sizes; (void)n_in; (void)out_size; (void)ws_size;
  const float* x  = (const float*)d_in[0];
  const float* Wq = (const float*)d_in[1];
  const float* bq = (const float*)d_in[2];
  const float* Wk = (const float*)d_in[3];
  const float* bk = (const float*)d_in[4];
  const float* Wv = (const float*)d_in[5];
  const float* bv = (const float*)d_in[6];
  const int* elen = (const int*)d_in[7];
  float* out = (float*)d_out;

  char* ws = (char*)d_ws;
  const size_t MB = 1024 * 1024;
  u16* xhi = (u16*)(ws + 0 * MB);
  u16* vtl_buf = (u16*)(ws + 8 * MB);
  u16* wqh = (u16*)(ws + 16 * MB); u16* wql = (u16*)(ws + 18 * MB);
  u16* wkh = (u16*)(ws + 20 * MB); u16* wkl = (u16*)(ws + 22 * MB);
  u16* wvh = (u16*)(ws + 24 * MB); u16* wvl = (u16*)(ws + 26 * MB);
  u16* qh  = (u16*)(ws + 28 * MB);
  u16* kh  = (u16*)(ws + 44 * MB); u16* kl  = (u16*)(ws + 52 * MB);
  u16* vh  = (u16*)(ws + 60 * MB); u16* vl  = (u16*)(ws + 68 * MB);
  u16* vth = xhi;  // alias: xhi dead after k_proj
  u16* vtl = vtl_buf;
  float* lacc = (float*)(ws + 76 * MB);           // 64K floats = 256 KB
  float* vsum = (float*)(ws + 76 * MB + 262144);  // 4K floats

  k_zero<<<4160, 256, 0, stream>>>(out, lacc);
  k_split_x<<<4096, 256, 0, stream>>>(x, xhi);
  k_wsplit<<<dim3(32, 32, 3), 256, 0, stream>>>(Wq, Wk, Wv, wqh, wql, wkh, wkl,
                                                wvh, wvl);
  k_proj<<<dim3(32, 8, 3), 256, 0, stream>>>(xhi, wqh, wql, wkh, wkl, wvh,
                                             wvl, bq, bk, bv, qh, /*ql=*/nullptr,
                                             kh, kl, vh, vl);
  k_vt<<<dim3(32, 2, 64), 256, 0, stream>>>(vh, vl, vth, vtl);
  k_vsum<<<1024, 256, 0, stream>>>(vth, vtl, vsum);
  k_attn_partial<<<dim3(64, 16, 4), 256, 0, stream>>>(qh, kh, kl, vth, vtl,
                                                      elen, out, lacc);
  k_finalize<<<4096, 256, 0, stream>>>(out, lacc, vsum, elen);
}

// Round 7
// 200.916 us; speedup vs baseline: 1.1083x; 1.1083x over previous
//
#include <hip/hip_runtime.h>
#include <stdint.h>

// ---------------------------------------------------------------------------
// MultiAttentionHead: B=4 S=1024 E=1024 H=16 D=64, fp32 in/out.
// GEMMs in bf16 MFMA with hi/lo split. Projections: 2 passes C ~= xh*(Wh+Wl).
// Attention: QK = qh*kh (k-lo dropped R7; err ~2e-3), PV = p*(vh+vl), p bf16,
// l summed from rounded p. Rows s >= len[b] get uniform attn = mean(V).
// R1: k_proj fused single-staging + XOR bank swizzle (0 conflicts measured).
// R2: wave-private P, DPP reductions, exp2 folding.
// R3: k_proj 2-pass + BK=64.
// R4: static softmax (no online max), C folded into q, P aliases Q's LDS.
// R5: (flash-decoding t-split -- REVERTED in R7: overhead > gain).
// R7: double-buffered K/V staging, ONE barrier per t-iter -- DMA for tile
//     t+1 overlaps compute of tile t, hiding the vmcnt(0) drain that was
//     ~2000-cyc/iter serial. K-lo dropped to fit dbuf in 64 KB static LDS.
// ---------------------------------------------------------------------------

using u16     = unsigned short;
using short8  = __attribute__((ext_vector_type(8))) short;
using floatx4 = __attribute__((ext_vector_type(4))) float;

#define MFMA(a, b, c) __builtin_amdgcn_mfma_f32_16x16x32_bf16(a, b, c, 0, 0, 0)

__device__ __forceinline__ float bf2f(u16 u) {
  uint32_t t = ((uint32_t)u) << 16; float f; __builtin_memcpy(&f, &t, 4); return f;
}
__device__ __forceinline__ u16 f2bf(float f) {  // round-to-nearest-even
  uint32_t x; __builtin_memcpy(&x, &f, 4);
  x += 0x7FFFu + ((x >> 16) & 1u);
  return (u16)(x >> 16);
}

// DPP rotate within aligned 16-lane rows (pure VALU; no LDS pipe).
template <int CTRL>
__device__ __forceinline__ float dppf(float v) {
  return __int_as_float(__builtin_amdgcn_update_dpp(
      0, __float_as_int(v), CTRL, 0xF, 0xF, true));
}
__device__ __forceinline__ float rowsum16(float v) {  // all-reduce sum, 16 lanes
  v += dppf<0x121>(v);
  v += dppf<0x122>(v);
  v += dppf<0x124>(v);
  v += dppf<0x128>(v);
  return v;
}

// async global->LDS DMA, 16B per lane. LDS dest must be wave-uniform base +
// lane*16 (no per-lane scatter) -- so bank swizzles permute the GLOBAL src.
__device__ __forceinline__ void async_cp16(void* lds, const void* g) {
  __builtin_amdgcn_global_load_lds(
      (__attribute__((address_space(1))) uint32_t*)(uintptr_t)g,
      (__attribute__((address_space(3))) uint32_t*)(uint32_t)(uintptr_t)lds,
      16, 0, 0);
}

// ---------------------------------------------------------------------------
// 1) split x (fp32) -> xhi (bf16)
// ---------------------------------------------------------------------------
__global__ void k_split_x(const float* __restrict__ x, u16* __restrict__ xhi) {
  int i = (blockIdx.x * 256 + threadIdx.x) * 4;
  float4 v = *(const float4*)(x + i);
  ushort4 hv;
  hv.x = f2bf(v.x);
  hv.y = f2bf(v.y);
  hv.z = f2bf(v.z);
  hv.w = f2bf(v.w);
  *(ushort4*)(xhi + i) = hv;
}

// ---------------------------------------------------------------------------
// 2) transpose + split weights: W[k][n] fp32 -> WT[n][k] bf16 hi/lo (B^T form)
// ---------------------------------------------------------------------------
__global__ void k_wsplit(const float* __restrict__ w0, const float* __restrict__ w1,
                         const float* __restrict__ w2,
                         u16* __restrict__ o0h, u16* __restrict__ o0l,
                         u16* __restrict__ o1h, u16* __restrict__ o1l,
                         u16* __restrict__ o2h, u16* __restrict__ o2l) {
  __shared__ float t[32][33];
  const int z = blockIdx.z;
  const float* W = z == 0 ? w0 : (z == 1 ? w1 : w2);
  u16* oh = z == 0 ? o0h : (z == 1 ? o1h : o2h);
  u16* ol = z == 0 ? o0l : (z == 1 ? o1l : o2l);
  const int kb = blockIdx.x * 32, nb = blockIdx.y * 32;
  const int tx = threadIdx.x & 31, ty = threadIdx.x >> 5;
  for (int r = ty; r < 32; r += 8) t[r][tx] = W[(kb + r) * 1024 + nb + tx];
  __syncthreads();
  for (int r = ty; r < 32; r += 8) {
    float v = t[tx][r];
    u16 hh = f2bf(v);
    int idx = (nb + r) * 1024 + kb + tx;
    oh[idx] = hh;
    ol[idx] = f2bf(v - bf2f(hh));
  }
}

// ---------------------------------------------------------------------------
// 3) projection GEMM: C[4096][1024] = xh @ (Wh + Wl) + b, 128x128 tile,
//    BK=64. LDS 48 KB: Ah + Bh + Bl [128][64], 8-chunk XOR swizzle.
//    q output (z==0) is pre-scaled by 0.125*log2(e) so k_attn can exp2 raw
//    scores. Output re-split to bf16 hi/lo, layout [B][H][S][D];
//    ol==nullptr skips the lo write (q and k paths).
// ---------------------------------------------------------------------------
__launch_bounds__(256, 3)
__global__ void k_proj(const u16* __restrict__ xhi,
                       const u16* __restrict__ wqh, const u16* __restrict__ wql,
                       const u16* __restrict__ wkh, const u16* __restrict__ wkl,
                       const u16* __restrict__ wvh, const u16* __restrict__ wvl,
                       const float* __restrict__ bq, const float* __restrict__ bk,
                       const float* __restrict__ bv,
                       u16* __restrict__ qh, u16* __restrict__ ql,
                       u16* __restrict__ kh, u16* __restrict__ kl,
                       u16* __restrict__ vh, u16* __restrict__ vl) {
  __shared__ u16 Sm[24576];  // Ah@0, Bh@8192, Bl@16384 -- each [128][64]
  const int z = blockIdx.z;
  const u16* wh = z == 0 ? wqh : (z == 1 ? wkh : wvh);
  const u16* wl = z == 0 ? wql : (z == 1 ? wkl : wvl);
  const float* bias = z == 0 ? bq : (z == 1 ? bk : bv);
  u16* oh = z == 0 ? qh : (z == 1 ? kh : vh);
  u16* ol = z == 0 ? ql : (z == 1 ? kl : vl);
  const float oscale = (z == 0) ? 0.18033688011112042f : 1.0f;  // 0.125*log2(e)

  const int tid = threadIdx.x, l = tid & 63, w = tid >> 6;
  const int quad = l >> 4, col = l & 15;
  const int m0 = blockIdx.x * 128, n0 = blockIdx.y * 128;
  const int wm = (w & 1) * 64, wn = (w >> 1) * 64;

  const int row0 = tid >> 3, ch = tid & 7;
  const int sc8 = (ch ^ (row0 & 7)) * 8;
  int gofs[4], lofs[4];
#pragma unroll
  for (int p = 0; p < 4; p++) {
    gofs[p] = (row0 + 32 * p) * 1024 + sc8;
    lofs[p] = (tid + p * 256) * 8;
  }

  const u16* Ag  = xhi + m0 * 1024;
  const u16* Bhg = wh + n0 * 1024;
  const u16* Blg = wl + n0 * 1024;

  int ar[2][4], br[2][4];
#pragma unroll
  for (int ks = 0; ks < 2; ks++) {
#pragma unroll
    for (int i = 0; i < 4; i++) {
      int r = wm + i * 16 + col;
      ar[ks][i] = r * 64 + (((ks * 4 + quad) ^ (r & 7)) * 8);
    }
#pragma unroll
    for (int j = 0; j < 4; j++) {
      int r = wn + j * 16 + col;
      br[ks][j] = r * 64 + (((ks * 4 + quad) ^ (r & 7)) * 8);
    }
  }

  floatx4 zero4 = {0.f, 0.f, 0.f, 0.f};
  floatx4 acc[4][4];
#pragma unroll
  for (int i = 0; i < 4; i++)
#pragma unroll
    for (int j = 0; j < 4; j++) acc[i][j] = zero4;

  for (int k0 = 0; k0 < 1024; k0 += 64) {
    __syncthreads();
#pragma unroll
    for (int p = 0; p < 4; p++) async_cp16(Sm + lofs[p], Ag + gofs[p] + k0);
#pragma unroll
    for (int p = 0; p < 4; p++)
      async_cp16(Sm + 8192 + lofs[p], Bhg + gofs[p] + k0);
#pragma unroll
    for (int p = 0; p < 4; p++)
      async_cp16(Sm + 16384 + lofs[p], Blg + gofs[p] + k0);
    __syncthreads();

#pragma unroll
    for (int ks = 0; ks < 2; ks++) {
      short8 fah[4], fbh[4];
#pragma unroll
      for (int i = 0; i < 4; i++) fah[i] = *(const short8*)(Sm + ar[ks][i]);
#pragma unroll
      for (int j = 0; j < 4; j++)
        fbh[j] = *(const short8*)(Sm + 8192 + br[ks][j]);
#pragma unroll
      for (int i = 0; i < 4; i++)
#pragma unroll
        for (int j = 0; j < 4; j++) acc[i][j] = MFMA(fah[i], fbh[j], acc[i][j]);

      short8 fbl[4];
#pragma unroll
      for (int j = 0; j < 4; j++)
        fbl[j] = *(const short8*)(Sm + 16384 + br[ks][j]);
#pragma unroll
      for (int i = 0; i < 4; i++)
#pragma unroll
        for (int j = 0; j < 4; j++) acc[i][j] = MFMA(fah[i], fbl[j], acc[i][j]);
    }
  }

  const bool wlo = (ol != nullptr);
#pragma unroll
  for (int j = 0; j < 4; j++) {
    int n = n0 + wn + j * 16 + col;
    float bb = bias[n];
    int hh = n >> 6, d = n & 63;
#pragma unroll
    for (int i = 0; i < 4; i++) {
      int mbase = m0 + wm + i * 16 + quad * 4;
#pragma unroll
      for (int r = 0; r < 4; r++) {
        int m = mbase + r;
        int bidx = m >> 10, s = m & 1023;
        float v = (acc[i][j][r] + bb) * oscale;
        int idx = ((bidx * 16 + hh) * 1024 + s) * 64 + d;
        u16 vh16 = f2bf(v);
        oh[idx] = vh16;
        if (wlo) ol[idx] = f2bf(v - bf2f(vh16));
      }
    }
  }
}

// ---------------------------------------------------------------------------
// 4) transpose V per (b,h): [S][D] -> [D][S] (hi & lo), LDS-tiled 32x32
// ---------------------------------------------------------------------------
__global__ void k_vt(const u16* __restrict__ vh, const u16* __restrict__ vl,
                     u16* __restrict__ vth, u16* __restrict__ vtl) {
  __shared__ u16 th[32][33], tl[32][33];
  const int bh = blockIdx.z, sb = blockIdx.x * 32, db = blockIdx.y * 32;
  const int tx = threadIdx.x & 31, ty = threadIdx.x >> 5;
  const u16* sh = vh + bh * 65536;
  const u16* sl = vl + bh * 65536;
  for (int r = ty; r < 32; r += 8) {
    th[r][tx] = sh[(sb + r) * 64 + db + tx];
    tl[r][tx] = sl[(sb + r) * 64 + db + tx];
  }
  __syncthreads();
  u16* dh = vth + bh * 65536;
  u16* dl = vtl + bh * 65536;
  for (int r = ty; r < 32; r += 8) {
    dh[(db + r) * 1024 + sb + tx] = th[tx][r];
    dl[(db + r) * 1024 + sb + tx] = tl[tx][r];
  }
}

// ---------------------------------------------------------------------------
// 5) vsum[bh*64+d] = sum_t V[b,h,t,d]  (for uniform-attention rows s>=len)
// ---------------------------------------------------------------------------
__global__ void k_vsum(const u16* __restrict__ vth, const u16* __restrict__ vtl,
                       float* __restrict__ vsum) {
  int row = blockIdx.x * 4 + (threadIdx.x >> 6);
  int l = threadIdx.x & 63;
  const u16* ph = vth + row * 1024;
  const u16* pl = vtl + row * 1024;
  float s = 0.f;
  for (int i = 0; i < 16; i++) {
    int t = i * 64 + l;
    s += bf2f(ph[t]) + bf2f(pl[t]);
  }
  for (int m = 32; m >= 1; m >>= 1) s += __shfl_xor(s, m, 64);
  if (l == 0) vsum[row] = s;
}

// ---------------------------------------------------------------------------
// Swizzled 64x64 bf16 tile stage (global -> LDS via DMA).
// ---------------------------------------------------------------------------
__device__ __forceinline__ void stage64(u16* lds, const u16* g, int row_stride,
                                        int tid) {
#pragma unroll
  for (int p = 0; p < 2; p++) {
    int slot = (p * 256 + tid) * 8;  // element index; *2 = bytes
    int row = slot >> 6;
    int gp = (slot >> 3) & 7;
    int gl = gp ^ (row & 7);
    async_cp16(lds + slot, g + row * row_stride + gl * 8);
  }
}

// ---------------------------------------------------------------------------
// 6) flash attention, static softmax, DOUBLE-BUFFERED staging (R7).
//    Block: one (b,h), 64 q-rows; t-tiles of 64. Per iter: issue DMA for
//    tile t+1 into ping, compute tile t from pong, ONE __syncthreads (its
//    vmcnt(0) drain overlaps the whole compute phase). QK uses kh only;
//    PV uses vh+vl. P aliases Q's LDS (wave-private rows).
//    LDS: QP 8K + 2 x (Kh 8K + VTh 8K + VTl 8K) = 56 KB -> 2 blocks/CU.
// ---------------------------------------------------------------------------
__launch_bounds__(256)
__global__ void k_attn(const u16* __restrict__ qh_g,
                       const u16* __restrict__ kh_g,
                       const u16* __restrict__ vth_g,
                       const u16* __restrict__ vtl_g,
                       const float* __restrict__ vsum, const int* __restrict__ elen,
                       float* __restrict__ out) {
  __shared__ u16 QP[4096];        // [64][64] swizzled: Q, then P (aliased)
  __shared__ u16 Bufs[2][12288];  // per buf: Kh@0, VTh@4096, VTl@8192
  const int tid = threadIdx.x, l = tid & 63, w = tid >> 6;
  const int quad = l >> 4, col = l & 15;
  const int bh = blockIdx.x, b = bh >> 4, h = bh & 15;
  const int q0 = blockIdx.y * 64;
  const int len = elen[b];

  if (q0 >= len) {  // fully-invalid tile: uniform attention over ALL t (ref)
    float val = vsum[bh * 64 + l] * (1.0f / 1024.0f);
    float* op = out + (b * 1024 + q0) * 1024 + h * 64 + l;
    for (int r = w; r < 64; r += 4) op[r * 1024] = val;
    return;
  }

  const u16* kh_b  = kh_g + bh * 65536;
  const u16* vth_b = vth_g + bh * 65536;
  const u16* vtl_b = vtl_g + bh * 65536;

  // prologue: stage Q + tile 0
  stage64(QP, qh_g + (bh * 1024 + q0) * 64, 64, tid);
  stage64(Bufs[0], kh_b, 64, tid);
  stage64(Bufs[0] + 4096, vth_b, 1024, tid);
  stage64(Bufs[0] + 8192, vtl_b, 1024, tid);
  __syncthreads();

  short8 qf[2];  // persistent Q fragments (A-layout: m=lane&15, k=quad*8+j)
  {
    int qrow = w * 16 + col;
#pragma unroll
    for (int ks = 0; ks < 2; ks++)
      qf[ks] = *(const short8*)(QP + qrow * 64 +
                                (((ks * 4 + quad) ^ (qrow & 7)) * 8));
  }

  // fragment offsets (same swizzle for K and VT tiles)
  int kvo[2][4];
#pragma unroll
  for (int ks = 0; ks < 2; ks++)
#pragma unroll
    for (int j = 0; j < 4; j++) {
      int n = j * 16 + col;
      kvo[ks][j] = n * 64 + (((ks * 4 + quad) ^ (n & 7)) * 8);
    }
  int p_rd[2];
#pragma unroll
  for (int ks = 0; ks < 2; ks++) {
    int row = w * 16 + col;
    p_rd[ks] = row * 64 + (((ks * 4 + quad) ^ (row & 7)) * 8);
  }
  int p_wr[4][4];
#pragma unroll
  for (int r = 0; r < 4; r++) {
    int row = w * 16 + quad * 4 + r;
#pragma unroll
    for (int j = 0; j < 4; j++) {
      int cj = j * 2 + (col >> 3);
      p_wr[r][j] = row * 64 + ((cj ^ (row & 7)) * 8) + (col & 7);
    }
  }

  floatx4 zero4 = {0.f, 0.f, 0.f, 0.f};
  floatx4 O[4];
  float lp[4];  // per-thread partial l (reduced after the loop)
#pragma unroll
  for (int j = 0; j < 4; j++) O[j] = zero4;
#pragma unroll
  for (int r = 0; r < 4; r++) lp[r] = 0.f;

  const int ntt = (len + 63) >> 6;
  for (int tt = 0; tt < ntt; ++tt) {
    const int t0 = tt * 64;
    u16* cur = Bufs[tt & 1];
    if (tt + 1 < ntt) {  // overlap: DMA tile t+1 while computing tile t
      u16* nxt = Bufs[(tt + 1) & 1];
      const int t1 = t0 + 64;
      stage64(nxt, kh_b + t1 * 64, 64, tid);
      stage64(nxt + 4096, vth_b + t1, 1024, tid);
      stage64(nxt + 8192, vtl_b + t1, 1024, tid);
    }

    // ---- raw scores = Q K^T (qh * kh); q carries 0.125*log2e ----
    floatx4 sc[4];
#pragma unroll
    for (int j = 0; j < 4; j++) sc[j] = zero4;
#pragma unroll
    for (int ks = 0; ks < 2; ks++) {
#pragma unroll
      for (int j = 0; j < 4; j++) {
        short8 kbh = *(const short8*)(cur + kvo[ks][j]);
        sc[j] = MFMA(qf[ks], kbh, sc[j]);
      }
    }

    if (t0 + 64 > len) {  // wave-uniform: only the last partial tile masks
#pragma unroll
      for (int j = 0; j < 4; j++) {
        bool inv = (t0 + j * 16 + col) >= len;
#pragma unroll
        for (int r = 0; r < 4; r++)
          if (inv) sc[j][r] = -3e38f;  // exp2 -> 0
      }
    }

    // ---- static softmax weights: p = exp2(score), bf16-rounded ----
#pragma unroll
    for (int r = 0; r < 4; r++) {
#pragma unroll
      for (int j = 0; j < 4; j++) {
        float e = __builtin_exp2f(sc[j][r]);
        u16 pe = f2bf(e);
        QP[p_wr[r][j]] = pe;   // wave-private rows; no barrier needed
        lp[r] += bf2f(pe);     // l sums the weights actually used
      }
    }

    // ---- O += P * (vh + vl) ----
#pragma unroll
    for (int ks = 0; ks < 2; ks++) {
      short8 pa = *(const short8*)(QP + p_rd[ks]);
#pragma unroll
      for (int j = 0; j < 4; j++) {
        short8 vbh = *(const short8*)(cur + 4096 + kvo[ks][j]);
        short8 vbl = *(const short8*)(cur + 8192 + kvo[ks][j]);
        O[j] = MFMA(pa, vbh, O[j]);
        O[j] = MFMA(pa, vbl, O[j]);
      }
    }

    __syncthreads();  // drain next-tile DMA (overlapped) + sync compute
  }

  // ---- epilogue: reduce l, normalize; per-row override for invalid rows ----
  float l_r[4];
#pragma unroll
  for (int r = 0; r < 4; r++) l_r[r] = rowsum16(lp[r]);
#pragma unroll
  for (int r = 0; r < 4; r++) {
    int s = q0 + w * 16 + quad * 4 + r;
    float invl = 1.0f / l_r[r];
    bool valid = (s < len);
#pragma unroll
    for (int j = 0; j < 4; j++) {
      int d = j * 16 + col;
      float val = valid ? O[j][r] * invl : vsum[bh * 64 + d] * (1.0f / 1024.0f);
      out[(b * 1024 + s) * 1024 + h * 64 + d] = val;
    }
  }
}

// ---------------------------------------------------------------------------
// launch
// ---------------------------------------------------------------------------
extern "C" void kernel_launch(void* const* d_in, const int* in_sizes, int n_in,
                              void* d_out, int out_size, void* d_ws, size_t ws_size,
                              hipStream_t stream) {
  (void)in_sizes; (void)n_in; (void)out_size; (void)ws_size;
  const float* x  = (const float*)d_in[0];
  const float* Wq = (const float*)d_in[1];
  const float* bq = (const float*)d_in[2];
  const float* Wk = (const float*)d_in[3];
  const float* bk = (const float*)d_in[4];
  const float* Wv = (const float*)d_in[5];
  const float* bv = (const float*)d_in[6];
  const int* elen = (const int*)d_in[7];
  float* out = (float*)d_out;

  char* ws = (char*)d_ws;
  const size_t MB = 1024 * 1024;
  u16* xhi = (u16*)(ws + 0 * MB);
  u16* vtl_buf = (u16*)(ws + 8 * MB);
  u16* wqh = (u16*)(ws + 16 * MB); u16* wql = (u16*)(ws + 18 * MB);
  u16* wkh = (u16*)(ws + 20 * MB); u16* wkl = (u16*)(ws + 22 * MB);
  u16* wvh = (u16*)(ws + 24 * MB); u16* wvl = (u16*)(ws + 26 * MB);
  u16* qh  = (u16*)(ws + 28 * MB);
  u16* kh  = (u16*)(ws + 44 * MB);
  u16* vh  = (u16*)(ws + 60 * MB); u16* vl  = (u16*)(ws + 68 * MB);
  u16* vth = xhi;  // alias: xhi dead after k_proj
  u16* vtl = vtl_buf;
  float* vsum = (float*)(ws + 76 * MB);

  k_split_x<<<4096, 256, 0, stream>>>(x, xhi);
  k_wsplit<<<dim3(32, 32, 3), 256, 0, stream>>>(Wq, Wk, Wv, wqh, wql, wkh, wkl,
                                                wvh, wvl);
  k_proj<<<dim3(32, 8, 3), 256, 0, stream>>>(xhi, wqh, wql, wkh, wkl, wvh,
                                             wvl, bq, bk, bv, qh, /*ql=*/nullptr,
                                             kh, /*kl=*/nullptr, vh, vl);
  k_vt<<<dim3(32, 2, 64), 256, 0, stream>>>(vh, vl, vth, vtl);
  k_vsum<<<1024, 256, 0, stream>>>(vth, vtl, vsum);
  k_attn<<<dim3(64, 16), 256, 0, stream>>>(qh, kh, vth, vtl, vsum, elen, out);
}

// Round 8
// 196.596 us; speedup vs baseline: 1.1326x; 1.0220x over previous
//
#include <hip/hip_runtime.h>
#include <stdint.h>

// ---------------------------------------------------------------------------
// MultiAttentionHead: B=4 S=1024 E=1024 H=16 D=64, fp32 in/out.
// GEMMs in bf16 MFMA with hi/lo split. Projections: 2 passes C ~= xh*(Wh+Wl).
// Attention: QK = qh*kh, PV = p*(vh+vl), p bf16, l summed from rounded p.
// Rows s >= len[b] get uniform attention = mean(V) per ref.
// R1: XOR bank swizzle staging (0 conflicts measured).
// R3: k_proj 2-pass + BK=64. R4: static softmax, C folded into q.
// R7: k_attn double-buffered staging, 1 barrier/iter.
// R8: k_proj epilogue staged through LDS -> 16B coalesced stores; z==2 blocks
//     write V^T hi/lo DIRECTLY (transposed via LDS) and reduce vsum from the
//     fp32 accumulators (atomicAdd; zeroed in k_prep). k_vt/k_vsum DELETED.
//     k_split_x + k_wsplit fused into k_prep. 3 kernels total.
// ---------------------------------------------------------------------------

using u16     = unsigned short;
using short8  = __attribute__((ext_vector_type(8))) short;
using floatx4 = __attribute__((ext_vector_type(4))) float;

#define MFMA(a, b, c) __builtin_amdgcn_mfma_f32_16x16x32_bf16(a, b, c, 0, 0, 0)

__device__ __forceinline__ float bf2f(u16 u) {
  uint32_t t = ((uint32_t)u) << 16; float f; __builtin_memcpy(&f, &t, 4); return f;
}
__device__ __forceinline__ u16 f2bf(float f) {  // round-to-nearest-even
  uint32_t x; __builtin_memcpy(&x, &f, 4);
  x += 0x7FFFu + ((x >> 16) & 1u);
  return (u16)(x >> 16);
}

// DPP rotate within aligned 16-lane rows (pure VALU; no LDS pipe).
template <int CTRL>
__device__ __forceinline__ float dppf(float v) {
  return __int_as_float(__builtin_amdgcn_update_dpp(
      0, __float_as_int(v), CTRL, 0xF, 0xF, true));
}
__device__ __forceinline__ float rowsum16(float v) {  // all-reduce sum, 16 lanes
  v += dppf<0x121>(v);
  v += dppf<0x122>(v);
  v += dppf<0x124>(v);
  v += dppf<0x128>(v);
  return v;
}

// async global->LDS DMA, 16B per lane. LDS dest must be wave-uniform base +
// lane*16 (no per-lane scatter) -- so bank swizzles permute the GLOBAL src.
__device__ __forceinline__ void async_cp16(void* lds, const void* g) {
  __builtin_amdgcn_global_load_lds(
      (__attribute__((address_space(1))) uint32_t*)(uintptr_t)g,
      (__attribute__((address_space(3))) uint32_t*)(uint32_t)(uintptr_t)lds,
      16, 0, 0);
}

// ---------------------------------------------------------------------------
// 1) prep (fused): blocks [0,4096): split x -> xhi bf16 (block 0 also zeroes
//    vsum); blocks [4096,7168): transpose+split weights -> WT hi/lo.
// ---------------------------------------------------------------------------
__global__ void k_prep(const float* __restrict__ x, u16* __restrict__ xhi,
                       const float* __restrict__ w0, const float* __restrict__ w1,
                       const float* __restrict__ w2,
                       u16* __restrict__ o0h, u16* __restrict__ o0l,
                       u16* __restrict__ o1h, u16* __restrict__ o1l,
                       u16* __restrict__ o2h, u16* __restrict__ o2l,
                       float* __restrict__ vsum) {
  __shared__ float t[32][33];
  const int bx = blockIdx.x;
  if (bx < 4096) {
    int i = (bx * 256 + threadIdx.x) * 4;
    float4 v = *(const float4*)(x + i);
    ushort4 hv;
    hv.x = f2bf(v.x);
    hv.y = f2bf(v.y);
    hv.z = f2bf(v.z);
    hv.w = f2bf(v.w);
    *(ushort4*)(xhi + i) = hv;
    if (bx == 0) {  // zero vsum (4096 floats) for k_proj's atomics
      float4 z = {0.f, 0.f, 0.f, 0.f};
#pragma unroll
      for (int e = 0; e < 4; e++) ((float4*)vsum)[threadIdx.x * 4 + e] = z;
    }
    return;
  }
  const int id = bx - 4096;                 // 0..3071
  const int z = id >> 10, rem = id & 1023;
  const float* W = z == 0 ? w0 : (z == 1 ? w1 : w2);
  u16* oh = z == 0 ? o0h : (z == 1 ? o1h : o2h);
  u16* ol = z == 0 ? o0l : (z == 1 ? o1l : o2l);
  const int kb = (rem & 31) * 32, nb = (rem >> 5) * 32;
  const int tx = threadIdx.x & 31, ty = threadIdx.x >> 5;
  for (int r = ty; r < 32; r += 8) t[r][tx] = W[(kb + r) * 1024 + nb + tx];
  __syncthreads();
  for (int r = ty; r < 32; r += 8) {
    float v = t[tx][r];
    u16 hh = f2bf(v);
    int idx = (nb + r) * 1024 + kb + tx;
    oh[idx] = hh;
    ol[idx] = f2bf(v - bf2f(hh));
  }
}

// ---------------------------------------------------------------------------
// 2) projection GEMM: C[4096][1024] = xh @ (Wh + Wl) + b, 128x128 tile,
//    BK=64, 8-chunk XOR swizzle (0 conflicts). Epilogue stages C through LDS
//    ([128][136] u16 pad: 16B-aligned rows, 2-way banks max) for 16B stores.
//    z=0/1 -> q/k hi in [B][H][S][D] (q pre-scaled by 0.125*log2e).
//    z=2   -> V^T hi/lo in [B][H][D][S] (transposed read from the LDS tile)
//             + vsum[bh*64+d] = sum_s v (fp32 acc, atomicAdd).
// ---------------------------------------------------------------------------
__launch_bounds__(256, 3)
__global__ void k_proj(const u16* __restrict__ xhi,
                       const u16* __restrict__ wqh, const u16* __restrict__ wql,
                       const u16* __restrict__ wkh, const u16* __restrict__ wkl,
                       const u16* __restrict__ wvh, const u16* __restrict__ wvl,
                       const float* __restrict__ bq, const float* __restrict__ bk,
                       const float* __restrict__ bv,
                       u16* __restrict__ qh, u16* __restrict__ kh,
                       u16* __restrict__ vth, u16* __restrict__ vtl,
                       float* __restrict__ vsum) {
  __shared__ u16 Sm[24576];  // K-loop: Ah@0, Bh@8192, Bl@16384 ([128][64]);
                             // epilogue: C tile [128][136]
  const int z = blockIdx.z;
  const u16* wh = z == 0 ? wqh : (z == 1 ? wkh : wvh);
  const u16* wl = z == 0 ? wql : (z == 1 ? wkl : wvl);
  const float* bias = z == 0 ? bq : (z == 1 ? bk : bv);
  u16* oh = z == 0 ? qh : (z == 1 ? kh : vth);
  const float oscale = (z == 0) ? 0.18033688011112042f : 1.0f;  // 0.125*log2(e)

  const int tid = threadIdx.x, l = tid & 63, w = tid >> 6;
  const int quad = l >> 4, col = l & 15;
  const int m0 = blockIdx.x * 128, n0 = blockIdx.y * 128;
  const int wm = (w & 1) * 64, wn = (w >> 1) * 64;

  const int row0 = tid >> 3, ch = tid & 7;
  const int sc8 = (ch ^ (row0 & 7)) * 8;
  int gofs[4], lofs[4];
#pragma unroll
  for (int p = 0; p < 4; p++) {
    gofs[p] = (row0 + 32 * p) * 1024 + sc8;
    lofs[p] = (tid + p * 256) * 8;
  }

  const u16* Ag  = xhi + m0 * 1024;
  const u16* Bhg = wh + n0 * 1024;
  const u16* Blg = wl + n0 * 1024;

  int ar[2][4], br[2][4];
#pragma unroll
  for (int ks = 0; ks < 2; ks++) {
#pragma unroll
    for (int i = 0; i < 4; i++) {
      int r = wm + i * 16 + col;
      ar[ks][i] = r * 64 + (((ks * 4 + quad) ^ (r & 7)) * 8);
    }
#pragma unroll
    for (int j = 0; j < 4; j++) {
      int r = wn + j * 16 + col;
      br[ks][j] = r * 64 + (((ks * 4 + quad) ^ (r & 7)) * 8);
    }
  }

  floatx4 zero4 = {0.f, 0.f, 0.f, 0.f};
  floatx4 acc[4][4];
#pragma unroll
  for (int i = 0; i < 4; i++)
#pragma unroll
    for (int j = 0; j < 4; j++) acc[i][j] = zero4;

  for (int k0 = 0; k0 < 1024; k0 += 64) {
    __syncthreads();
#pragma unroll
    for (int p = 0; p < 4; p++) async_cp16(Sm + lofs[p], Ag + gofs[p] + k0);
#pragma unroll
    for (int p = 0; p < 4; p++)
      async_cp16(Sm + 8192 + lofs[p], Bhg + gofs[p] + k0);
#pragma unroll
    for (int p = 0; p < 4; p++)
      async_cp16(Sm + 16384 + lofs[p], Blg + gofs[p] + k0);
    __syncthreads();

#pragma unroll
    for (int ks = 0; ks < 2; ks++) {
      short8 fah[4], fbh[4];
#pragma unroll
      for (int i = 0; i < 4; i++) fah[i] = *(const short8*)(Sm + ar[ks][i]);
#pragma unroll
      for (int j = 0; j < 4; j++)
        fbh[j] = *(const short8*)(Sm + 8192 + br[ks][j]);
#pragma unroll
      for (int i = 0; i < 4; i++)
#pragma unroll
        for (int j = 0; j < 4; j++) acc[i][j] = MFMA(fah[i], fbh[j], acc[i][j]);

      short8 fbl[4];
#pragma unroll
      for (int j = 0; j < 4; j++)
        fbl[j] = *(const short8*)(Sm + 16384 + br[ks][j]);
#pragma unroll
      for (int i = 0; i < 4; i++)
#pragma unroll
        for (int j = 0; j < 4; j++) acc[i][j] = MFMA(fah[i], fbl[j], acc[i][j]);
    }
  }

  // ---- epilogue: stage C tile in LDS ([128][136]) for coalesced stores ----
  const int bidx = m0 >> 10;     // batch index (uniform: 128 | 1024)
  const int sbase = m0 & 1023;
  __syncthreads();  // all K-loop LDS reads done before overwrite

#pragma unroll
  for (int j = 0; j < 4; j++) {
    int nloc = wn + j * 16 + col;
    float bb = bias[n0 + nloc];
#pragma unroll
    for (int i = 0; i < 4; i++)
#pragma unroll
      for (int r = 0; r < 4; r++) {
        int mloc = wm + i * 16 + quad * 4 + r;
        Sm[mloc * 136 + nloc] = f2bf((acc[i][j][r] + bb) * oscale);
      }
  }
  __syncthreads();

  if (z != 2) {
    // q/k hi: [bh][s][64] -- row-contiguous 16B chunks
#pragma unroll
    for (int k = 0; k < 8; k++) {
      int c = tid + k * 256;
      int mloc = c >> 4, n = (c & 15) * 8;
      int hh = (n0 + n) >> 6, d = (n0 + n) & 63;
      short8 vv = *(const short8*)(Sm + mloc * 136 + n);
      *(short8*)(oh + ((bidx * 16 + hh) * 1024 + sbase + mloc) * 64 + d) = vv;
    }
  } else {
    // V^T hi: [bh][d][1024] -- transposed read, s-contiguous 16B stores
#pragma unroll
    for (int k = 0; k < 8; k++) {
      int c = tid + k * 256;
      int nloc = c & 127, s0 = (c >> 7) * 8;
      int hh = (n0 + nloc) >> 6, d = (n0 + nloc) & 63;
      u16 tmp[8];
#pragma unroll
      for (int e = 0; e < 8; e++) tmp[e] = Sm[(s0 + e) * 136 + nloc];
      *(short8*)(vth + ((bidx * 16 + hh) * 64 + d) * 1024 + sbase + s0) =
          *(short8*)tmp;
    }
    __syncthreads();
    // lo pass
#pragma unroll
    for (int j = 0; j < 4; j++) {
      int nloc = wn + j * 16 + col;
      float bb = bias[n0 + nloc];
#pragma unroll
      for (int i = 0; i < 4; i++)
#pragma unroll
        for (int r = 0; r < 4; r++) {
          int mloc = wm + i * 16 + quad * 4 + r;
          float v = acc[i][j][r] + bb;
          Sm[mloc * 136 + nloc] = f2bf(v - bf2f(f2bf(v)));
        }
    }
    __syncthreads();
#pragma unroll
    for (int k = 0; k < 8; k++) {
      int c = tid + k * 256;
      int nloc = c & 127, s0 = (c >> 7) * 8;
      int hh = (n0 + nloc) >> 6, d = (n0 + nloc) & 63;
      u16 tmp[8];
#pragma unroll
      for (int e = 0; e < 8; e++) tmp[e] = Sm[(s0 + e) * 136 + nloc];
      *(short8*)(vtl + ((bidx * 16 + hh) * 64 + d) * 1024 + sbase + s0) =
          *(short8*)tmp;
    }
    // vsum partials from fp32 acc: vsum[bh*64+d] += sum over this block's s
#pragma unroll
    for (int j = 0; j < 4; j++) {
      int nloc = wn + j * 16 + col;
      float bb = bias[n0 + nloc];
      float part = 16.0f * bb;
#pragma unroll
      for (int i = 0; i < 4; i++)
#pragma unroll
        for (int r = 0; r < 4; r++) part += acc[i][j][r];
      part += __shfl_xor(part, 16, 64);  // reduce across quads (same n)
      part += __shfl_xor(part, 32, 64);
      if (quad == 0) {
        int hh = (n0 + nloc) >> 6, d = (n0 + nloc) & 63;
        unsafeAtomicAdd(vsum + (bidx * 16 + hh) * 64 + d, part);
      }
    }
  }
}

// ---------------------------------------------------------------------------
// Swizzled 64x64 bf16 tile stage (global -> LDS via DMA).
// ---------------------------------------------------------------------------
__device__ __forceinline__ void stage64(u16* lds, const u16* g, int row_stride,
                                        int tid) {
#pragma unroll
  for (int p = 0; p < 2; p++) {
    int slot = (p * 256 + tid) * 8;  // element index; *2 = bytes
    int row = slot >> 6;
    int gp = (slot >> 3) & 7;
    int gl = gp ^ (row & 7);
    async_cp16(lds + slot, g + row * row_stride + gl * 8);
  }
}

// ---------------------------------------------------------------------------
// 3) flash attention, static softmax, double-buffered staging.
//    Block: one (b,h), 64 q-rows; t-tiles of 64. Per iter: DMA tile t+1 into
//    ping, compute tile t from pong, ONE __syncthreads. QK uses kh only;
//    PV uses vh+vl. P aliases Q's LDS (wave-private rows).
//    LDS: QP 8K + 2 x 12K = 56 KB -> 2 blocks/CU.
// ---------------------------------------------------------------------------
__launch_bounds__(256)
__global__ void k_attn(const u16* __restrict__ qh_g,
                       const u16* __restrict__ kh_g,
                       const u16* __restrict__ vth_g,
                       const u16* __restrict__ vtl_g,
                       const float* __restrict__ vsum, const int* __restrict__ elen,
                       float* __restrict__ out) {
  __shared__ u16 QP[4096];        // [64][64] swizzled: Q, then P (aliased)
  __shared__ u16 Bufs[2][12288];  // per buf: Kh@0, VTh@4096, VTl@8192
  const int tid = threadIdx.x, l = tid & 63, w = tid >> 6;
  const int quad = l >> 4, col = l & 15;
  const int bh = blockIdx.x, b = bh >> 4, h = bh & 15;
  const int q0 = blockIdx.y * 64;
  const int len = elen[b];

  if (q0 >= len) {  // fully-invalid tile: uniform attention over ALL t (ref)
    float val = vsum[bh * 64 + l] * (1.0f / 1024.0f);
    float* op = out + (b * 1024 + q0) * 1024 + h * 64 + l;
    for (int r = w; r < 64; r += 4) op[r * 1024] = val;
    return;
  }

  const u16* kh_b  = kh_g + bh * 65536;
  const u16* vth_b = vth_g + bh * 65536;
  const u16* vtl_b = vtl_g + bh * 65536;

  // prologue: stage Q + tile 0
  stage64(QP, qh_g + (bh * 1024 + q0) * 64, 64, tid);
  stage64(Bufs[0], kh_b, 64, tid);
  stage64(Bufs[0] + 4096, vth_b, 1024, tid);
  stage64(Bufs[0] + 8192, vtl_b, 1024, tid);
  __syncthreads();

  short8 qf[2];  // persistent Q fragments (A-layout: m=lane&15, k=quad*8+j)
  {
    int qrow = w * 16 + col;
#pragma unroll
    for (int ks = 0; ks < 2; ks++)
      qf[ks] = *(const short8*)(QP + qrow * 64 +
                                (((ks * 4 + quad) ^ (qrow & 7)) * 8));
  }

  // fragment offsets (same swizzle for K and VT tiles)
  int kvo[2][4];
#pragma unroll
  for (int ks = 0; ks < 2; ks++)
#pragma unroll
    for (int j = 0; j < 4; j++) {
      int n = j * 16 + col;
      kvo[ks][j] = n * 64 + (((ks * 4 + quad) ^ (n & 7)) * 8);
    }
  int p_rd[2];
#pragma unroll
  for (int ks = 0; ks < 2; ks++) {
    int row = w * 16 + col;
    p_rd[ks] = row * 64 + (((ks * 4 + quad) ^ (row & 7)) * 8);
  }
  int p_wr[4][4];
#pragma unroll
  for (int r = 0; r < 4; r++) {
    int row = w * 16 + quad * 4 + r;
#pragma unroll
    for (int j = 0; j < 4; j++) {
      int cj = j * 2 + (col >> 3);
      p_wr[r][j] = row * 64 + ((cj ^ (row & 7)) * 8) + (col & 7);
    }
  }

  floatx4 zero4 = {0.f, 0.f, 0.f, 0.f};
  floatx4 O[4];
  float lp[4];  // per-thread partial l (reduced after the loop)
#pragma unroll
  for (int j = 0; j < 4; j++) O[j] = zero4;
#pragma unroll
  for (int r = 0; r < 4; r++) lp[r] = 0.f;

  const int ntt = (len + 63) >> 6;
  for (int tt = 0; tt < ntt; ++tt) {
    const int t0 = tt * 64;
    u16* cur = Bufs[tt & 1];
    if (tt + 1 < ntt) {  // overlap: DMA tile t+1 while computing tile t
      u16* nxt = Bufs[(tt + 1) & 1];
      const int t1 = t0 + 64;
      stage64(nxt, kh_b + t1 * 64, 64, tid);
      stage64(nxt + 4096, vth_b + t1, 1024, tid);
      stage64(nxt + 8192, vtl_b + t1, 1024, tid);
    }

    // ---- raw scores = Q K^T (qh * kh); q carries 0.125*log2e ----
    floatx4 sc[4];
#pragma unroll
    for (int j = 0; j < 4; j++) sc[j] = zero4;
#pragma unroll
    for (int ks = 0; ks < 2; ks++) {
#pragma unroll
      for (int j = 0; j < 4; j++) {
        short8 kbh = *(const short8*)(cur + kvo[ks][j]);
        sc[j] = MFMA(qf[ks], kbh, sc[j]);
      }
    }

    if (t0 + 64 > len) {  // wave-uniform: only the last partial tile masks
#pragma unroll
      for (int j = 0; j < 4; j++) {
        bool inv = (t0 + j * 16 + col) >= len;
#pragma unroll
        for (int r = 0; r < 4; r++)
          if (inv) sc[j][r] = -3e38f;  // exp2 -> 0
      }
    }

    // ---- static softmax weights: p = exp2(score), bf16-rounded ----
#pragma unroll
    for (int r = 0; r < 4; r++) {
#pragma unroll
      for (int j = 0; j < 4; j++) {
        float e = __builtin_exp2f(sc[j][r]);
        u16 pe = f2bf(e);
        QP[p_wr[r][j]] = pe;   // wave-private rows; no barrier needed
        lp[r] += bf2f(pe);     // l sums the weights actually used
      }
    }

    // ---- O += P * (vh + vl) ----
#pragma unroll
    for (int ks = 0; ks < 2; ks++) {
      short8 pa = *(const short8*)(QP + p_rd[ks]);
#pragma unroll
      for (int j = 0; j < 4; j++) {
        short8 vbh = *(const short8*)(cur + 4096 + kvo[ks][j]);
        short8 vbl = *(const short8*)(cur + 8192 + kvo[ks][j]);
        O[j] = MFMA(pa, vbh, O[j]);
        O[j] = MFMA(pa, vbl, O[j]);
      }
    }

    __syncthreads();  // drain next-tile DMA (overlapped) + sync compute
  }

  // ---- epilogue: reduce l, normalize; per-row override for invalid rows ----
  float l_r[4];
#pragma unroll
  for (int r = 0; r < 4; r++) l_r[r] = rowsum16(lp[r]);
#pragma unroll
  for (int r = 0; r < 4; r++) {
    int s = q0 + w * 16 + quad * 4 + r;
    float invl = 1.0f / l_r[r];
    bool valid = (s < len);
#pragma unroll
    for (int j = 0; j < 4; j++) {
      int d = j * 16 + col;
      float val = valid ? O[j][r] * invl : vsum[bh * 64 + d] * (1.0f / 1024.0f);
      out[(b * 1024 + s) * 1024 + h * 64 + d] = val;
    }
  }
}

// ---------------------------------------------------------------------------
// launch
// ---------------------------------------------------------------------------
extern "C" void kernel_launch(void* const* d_in, const int* in_sizes, int n_in,
                              void* d_out, int out_size, void* d_ws, size_t ws_size,
                              hipStream_t stream) {
  (void)in_sizes; (void)n_in; (void)out_size; (void)ws_size;
  const float* x  = (const float*)d_in[0];
  const float* Wq = (const float*)d_in[1];
  const float* bq = (const float*)d_in[2];
  const float* Wk = (const float*)d_in[3];
  const float* bk = (const float*)d_in[4];
  const float* Wv = (const float*)d_in[5];
  const float* bv = (const float*)d_in[6];
  const int* elen = (const int*)d_in[7];
  float* out = (float*)d_out;

  char* ws = (char*)d_ws;
  const size_t MB = 1024 * 1024;
  u16* xhi = (u16*)(ws + 0 * MB);
  u16* vtl = (u16*)(ws + 8 * MB);
  u16* wqh = (u16*)(ws + 16 * MB); u16* wql = (u16*)(ws + 18 * MB);
  u16* wkh = (u16*)(ws + 20 * MB); u16* wkl = (u16*)(ws + 22 * MB);
  u16* wvh = (u16*)(ws + 24 * MB); u16* wvl = (u16*)(ws + 26 * MB);
  u16* qh  = (u16*)(ws + 28 * MB);
  u16* kh  = (u16*)(ws + 36 * MB);
  u16* vth = (u16*)(ws + 44 * MB);
  float* vsum = (float*)(ws + 52 * MB);  // 4096 floats

  k_prep<<<7168, 256, 0, stream>>>(x, xhi, Wq, Wk, Wv, wqh, wql, wkh, wkl,
                                   wvh, wvl, vsum);
  k_proj<<<dim3(32, 8, 3), 256, 0, stream>>>(xhi, wqh, wql, wkh, wkl, wvh,
                                             wvl, bq, bk, bv, qh, kh, vth, vtl,
                                             vsum);
  k_attn<<<dim3(64, 16), 256, 0, stream>>>(qh, kh, vth, vtl, vsum, elen, out);
}

// Round 9
// 192.433 us; speedup vs baseline: 1.1571x; 1.0216x over previous
//
#include <hip/hip_runtime.h>
#include <stdint.h>

// ---------------------------------------------------------------------------
// MultiAttentionHead: B=4 S=1024 E=1024 H=16 D=64, fp32 in/out.
// GEMMs in bf16 MFMA with hi/lo split. Projections: 2 passes C ~= xh*(Wh+Wl).
// Attention: QK = qh*kh, PV = p*(vh+vl), p bf16, l summed from rounded p.
// Rows s >= len[b] get uniform attention = mean(V) per ref.
// R1: XOR bank swizzle staging (0 conflicts measured).
// R3: k_proj 2-pass. R4: static softmax, C folded into q.
// R7: k_attn double-buffered staging, 1 barrier/iter.
// R8: LDS-staged epilogue (WRITE_SIZE 61->33 MB confirmed), direct V^T +
//     vsum from accs, fused prep. 3 kernels.
// R9: k_proj K-loop restructured: BK=32 DOUBLE-BUFFERED (2 x 24 KB), one
//     barrier/iter -- DMA for tile k+1 overlaps the 32-MFMA compute of tile
//     k, attacking the ~23% vmcnt(0) drain stall of the 2-barrier structure
//     (same fix that broke k_attn's plateau in R7).
// ---------------------------------------------------------------------------

using u16     = unsigned short;
using short8  = __attribute__((ext_vector_type(8))) short;
using floatx4 = __attribute__((ext_vector_type(4))) float;

#define MFMA(a, b, c) __builtin_amdgcn_mfma_f32_16x16x32_bf16(a, b, c, 0, 0, 0)

__device__ __forceinline__ float bf2f(u16 u) {
  uint32_t t = ((uint32_t)u) << 16; float f; __builtin_memcpy(&f, &t, 4); return f;
}
__device__ __forceinline__ u16 f2bf(float f) {  // round-to-nearest-even
  uint32_t x; __builtin_memcpy(&x, &f, 4);
  x += 0x7FFFu + ((x >> 16) & 1u);
  return (u16)(x >> 16);
}

// DPP rotate within aligned 16-lane rows (pure VALU; no LDS pipe).
template <int CTRL>
__device__ __forceinline__ float dppf(float v) {
  return __int_as_float(__builtin_amdgcn_update_dpp(
      0, __float_as_int(v), CTRL, 0xF, 0xF, true));
}
__device__ __forceinline__ float rowsum16(float v) {  // all-reduce sum, 16 lanes
  v += dppf<0x121>(v);
  v += dppf<0x122>(v);
  v += dppf<0x124>(v);
  v += dppf<0x128>(v);
  return v;
}

// async global->LDS DMA, 16B per lane. LDS dest must be wave-uniform base +
// lane*16 (no per-lane scatter) -- so bank swizzles permute the GLOBAL src.
__device__ __forceinline__ void async_cp16(void* lds, const void* g) {
  __builtin_amdgcn_global_load_lds(
      (__attribute__((address_space(1))) uint32_t*)(uintptr_t)g,
      (__attribute__((address_space(3))) uint32_t*)(uint32_t)(uintptr_t)lds,
      16, 0, 0);
}

// ---------------------------------------------------------------------------
// 1) prep (fused): blocks [0,4096): split x -> xhi bf16 (block 0 also zeroes
//    vsum); blocks [4096,7168): transpose+split weights -> WT hi/lo.
// ---------------------------------------------------------------------------
__global__ void k_prep(const float* __restrict__ x, u16* __restrict__ xhi,
                       const float* __restrict__ w0, const float* __restrict__ w1,
                       const float* __restrict__ w2,
                       u16* __restrict__ o0h, u16* __restrict__ o0l,
                       u16* __restrict__ o1h, u16* __restrict__ o1l,
                       u16* __restrict__ o2h, u16* __restrict__ o2l,
                       float* __restrict__ vsum) {
  __shared__ float t[32][33];
  const int bx = blockIdx.x;
  if (bx < 4096) {
    int i = (bx * 256 + threadIdx.x) * 4;
    float4 v = *(const float4*)(x + i);
    ushort4 hv;
    hv.x = f2bf(v.x);
    hv.y = f2bf(v.y);
    hv.z = f2bf(v.z);
    hv.w = f2bf(v.w);
    *(ushort4*)(xhi + i) = hv;
    if (bx == 0) {  // zero vsum (4096 floats) for k_proj's atomics
      float4 z = {0.f, 0.f, 0.f, 0.f};
#pragma unroll
      for (int e = 0; e < 4; e++) ((float4*)vsum)[threadIdx.x * 4 + e] = z;
    }
    return;
  }
  const int id = bx - 4096;                 // 0..3071
  const int z = id >> 10, rem = id & 1023;
  const float* W = z == 0 ? w0 : (z == 1 ? w1 : w2);
  u16* oh = z == 0 ? o0h : (z == 1 ? o1h : o2h);
  u16* ol = z == 0 ? o0l : (z == 1 ? o1l : o2l);
  const int kb = (rem & 31) * 32, nb = (rem >> 5) * 32;
  const int tx = threadIdx.x & 31, ty = threadIdx.x >> 5;
  for (int r = ty; r < 32; r += 8) t[r][tx] = W[(kb + r) * 1024 + nb + tx];
  __syncthreads();
  for (int r = ty; r < 32; r += 8) {
    float v = t[tx][r];
    u16 hh = f2bf(v);
    int idx = (nb + r) * 1024 + kb + tx;
    oh[idx] = hh;
    ol[idx] = f2bf(v - bf2f(hh));
  }
}

// ---------------------------------------------------------------------------
// 2) projection GEMM: C[4096][1024] = xh @ (Wh + Wl) + b, 128x128 tile,
//    BK=32 DOUBLE-BUFFERED (R9): per iter, DMA tile k+1 into the ping buffer
//    (6 x 16B/thread), compute 32 MFMAs from pong, ONE barrier. 4-chunk XOR
//    swizzle (chunk ^= (row>>1)&3, 0 conflicts -- R1). Epilogue stages C
//    through LDS ([128][136]) for 16B stores (R8). z=0/1 -> q/k hi in
//    [B][H][S][D] (q pre-scaled by 0.125*log2e); z=2 -> V^T hi/lo in
//    [B][H][D][S] + vsum (fp32 accs, atomicAdd).
// ---------------------------------------------------------------------------
__launch_bounds__(256, 3)
__global__ void k_proj(const u16* __restrict__ xhi,
                       const u16* __restrict__ wqh, const u16* __restrict__ wql,
                       const u16* __restrict__ wkh, const u16* __restrict__ wkl,
                       const u16* __restrict__ wvh, const u16* __restrict__ wvl,
                       const float* __restrict__ bq, const float* __restrict__ bk,
                       const float* __restrict__ bv,
                       u16* __restrict__ qh, u16* __restrict__ kh,
                       u16* __restrict__ vth, u16* __restrict__ vtl,
                       float* __restrict__ vsum) {
  __shared__ u16 Sm[24576];  // dbuf b@b*12288: A@0, Bh@4096, Bl@8192
                             // (each [128][32]); epilogue: C tile [128][136]
  const int z = blockIdx.z;
  const u16* wh = z == 0 ? wqh : (z == 1 ? wkh : wvh);
  const u16* wl = z == 0 ? wql : (z == 1 ? wkl : wvl);
  const float* bias = z == 0 ? bq : (z == 1 ? bk : bv);
  u16* oh = z == 0 ? qh : (z == 1 ? kh : vth);
  const float oscale = (z == 0) ? 0.18033688011112042f : 1.0f;  // 0.125*log2(e)

  const int tid = threadIdx.x, l = tid & 63, w = tid >> 6;
  const int quad = l >> 4, col = l & 15;
  const int m0 = blockIdx.x * 128, n0 = blockIdx.y * 128;
  const int wm = (w & 1) * 64, wn = (w >> 1) * 64;

  // staging: thread covers LDS slots tid*8 and 2048+tid*8 per tile; global
  // src chunk XOR-swizzled per row ((row+64)>>1 & 3 == (row>>1)&3).
  const int row0 = tid >> 2, pc = tid & 3;
  const int g0 = row0 * 1024 + ((pc ^ ((row0 >> 1) & 3)) * 8);
  const int g1 = (row0 + 64) * 1024 + ((pc ^ ((row0 >> 1) & 3)) * 8);
  const int l0 = tid * 8, l1 = 2048 + tid * 8;

  const u16* Ag  = xhi + m0 * 1024;
  const u16* Bhg = wh + n0 * 1024;
  const u16* Blg = wl + n0 * 1024;

  // fragment LDS offsets (reader applies the same swizzle)
  int ar[4], br[4];
#pragma unroll
  for (int i = 0; i < 4; i++) {
    int r = wm + i * 16 + col;
    ar[i] = r * 32 + ((quad ^ ((r >> 1) & 3)) * 8);
  }
#pragma unroll
  for (int j = 0; j < 4; j++) {
    int r = wn + j * 16 + col;
    br[j] = r * 32 + ((quad ^ ((r >> 1) & 3)) * 8);
  }

  floatx4 zero4 = {0.f, 0.f, 0.f, 0.f};
  floatx4 acc[4][4];
#pragma unroll
  for (int i = 0; i < 4; i++)
#pragma unroll
    for (int j = 0; j < 4; j++) acc[i][j] = zero4;

  // prologue: stage k-tile 0 into buffer 0
  async_cp16(Sm + l0,        Ag + g0);
  async_cp16(Sm + l1,        Ag + g1);
  async_cp16(Sm + 4096 + l0, Bhg + g0);
  async_cp16(Sm + 4096 + l1, Bhg + g1);
  async_cp16(Sm + 8192 + l0, Blg + g0);
  async_cp16(Sm + 8192 + l1, Blg + g1);
  __syncthreads();

  for (int kt = 0; kt < 32; ++kt) {
    u16* cur = Sm + (kt & 1) * 12288;
    if (kt + 1 < 32) {  // overlap: DMA tile k+1 while computing tile k
      u16* nxt = Sm + ((kt + 1) & 1) * 12288;
      const int k0 = (kt + 1) * 32;
      async_cp16(nxt + l0,        Ag + g0 + k0);
      async_cp16(nxt + l1,        Ag + g1 + k0);
      async_cp16(nxt + 4096 + l0, Bhg + g0 + k0);
      async_cp16(nxt + 4096 + l1, Bhg + g1 + k0);
      async_cp16(nxt + 8192 + l0, Blg + g0 + k0);
      async_cp16(nxt + 8192 + l1, Blg + g1 + k0);
    }

    short8 fah[4], fbh[4];
#pragma unroll
    for (int i = 0; i < 4; i++) fah[i] = *(const short8*)(cur + ar[i]);
#pragma unroll
    for (int j = 0; j < 4; j++) fbh[j] = *(const short8*)(cur + 4096 + br[j]);
#pragma unroll
    for (int i = 0; i < 4; i++)
#pragma unroll
      for (int j = 0; j < 4; j++) acc[i][j] = MFMA(fah[i], fbh[j], acc[i][j]);

    short8 fbl[4];
#pragma unroll
    for (int j = 0; j < 4; j++) fbl[j] = *(const short8*)(cur + 8192 + br[j]);
#pragma unroll
    for (int i = 0; i < 4; i++)
#pragma unroll
      for (int j = 0; j < 4; j++) acc[i][j] = MFMA(fah[i], fbl[j], acc[i][j]);

    __syncthreads();  // drain next-tile DMA (overlapped) + sync compute
  }

  // ---- epilogue: stage C tile in LDS ([128][136]) for coalesced stores ----
  const int bidx = m0 >> 10;     // batch index (uniform: 128 | 1024)
  const int sbase = m0 & 1023;
  // loop ended with __syncthreads(): all LDS reads done, safe to overwrite

#pragma unroll
  for (int j = 0; j < 4; j++) {
    int nloc = wn + j * 16 + col;
    float bb = bias[n0 + nloc];
#pragma unroll
    for (int i = 0; i < 4; i++)
#pragma unroll
      for (int r = 0; r < 4; r++) {
        int mloc = wm + i * 16 + quad * 4 + r;
        Sm[mloc * 136 + nloc] = f2bf((acc[i][j][r] + bb) * oscale);
      }
  }
  __syncthreads();

  if (z != 2) {
    // q/k hi: [bh][s][64] -- row-contiguous 16B chunks
#pragma unroll
    for (int k = 0; k < 8; k++) {
      int c = tid + k * 256;
      int mloc = c >> 4, n = (c & 15) * 8;
      int hh = (n0 + n) >> 6, d = (n0 + n) & 63;
      short8 vv = *(const short8*)(Sm + mloc * 136 + n);
      *(short8*)(oh + ((bidx * 16 + hh) * 1024 + sbase + mloc) * 64 + d) = vv;
    }
  } else {
    // V^T hi: [bh][d][1024] -- transposed read, s-contiguous 16B stores
#pragma unroll
    for (int k = 0; k < 8; k++) {
      int c = tid + k * 256;
      int nloc = c & 127, s0 = (c >> 7) * 8;
      int hh = (n0 + nloc) >> 6, d = (n0 + nloc) & 63;
      u16 tmp[8];
#pragma unroll
      for (int e = 0; e < 8; e++) tmp[e] = Sm[(s0 + e) * 136 + nloc];
      *(short8*)(vth + ((bidx * 16 + hh) * 64 + d) * 1024 + sbase + s0) =
          *(short8*)tmp;
    }
    __syncthreads();
    // lo pass
#pragma unroll
    for (int j = 0; j < 4; j++) {
      int nloc = wn + j * 16 + col;
      float bb = bias[n0 + nloc];
#pragma unroll
      for (int i = 0; i < 4; i++)
#pragma unroll
        for (int r = 0; r < 4; r++) {
          int mloc = wm + i * 16 + quad * 4 + r;
          float v = acc[i][j][r] + bb;
          Sm[mloc * 136 + nloc] = f2bf(v - bf2f(f2bf(v)));
        }
    }
    __syncthreads();
#pragma unroll
    for (int k = 0; k < 8; k++) {
      int c = tid + k * 256;
      int nloc = c & 127, s0 = (c >> 7) * 8;
      int hh = (n0 + nloc) >> 6, d = (n0 + nloc) & 63;
      u16 tmp[8];
#pragma unroll
      for (int e = 0; e < 8; e++) tmp[e] = Sm[(s0 + e) * 136 + nloc];
      *(short8*)(vtl + ((bidx * 16 + hh) * 64 + d) * 1024 + sbase + s0) =
          *(short8*)tmp;
    }
    // vsum partials from fp32 acc: vsum[bh*64+d] += sum over this block's s
#pragma unroll
    for (int j = 0; j < 4; j++) {
      int nloc = wn + j * 16 + col;
      float bb = bias[n0 + nloc];
      float part = 16.0f * bb;
#pragma unroll
      for (int i = 0; i < 4; i++)
#pragma unroll
        for (int r = 0; r < 4; r++) part += acc[i][j][r];
      part += __shfl_xor(part, 16, 64);  // reduce across quads (same n)
      part += __shfl_xor(part, 32, 64);
      if (quad == 0) {
        int hh = (n0 + nloc) >> 6, d = (n0 + nloc) & 63;
        unsafeAtomicAdd(vsum + (bidx * 16 + hh) * 64 + d, part);
      }
    }
  }
}

// ---------------------------------------------------------------------------
// Swizzled 64x64 bf16 tile stage (global -> LDS via DMA).
// ---------------------------------------------------------------------------
__device__ __forceinline__ void stage64(u16* lds, const u16* g, int row_stride,
                                        int tid) {
#pragma unroll
  for (int p = 0; p < 2; p++) {
    int slot = (p * 256 + tid) * 8;  // element index; *2 = bytes
    int row = slot >> 6;
    int gp = (slot >> 3) & 7;
    int gl = gp ^ (row & 7);
    async_cp16(lds + slot, g + row * row_stride + gl * 8);
  }
}

// ---------------------------------------------------------------------------
// 3) flash attention, static softmax, double-buffered staging.
//    Block: one (b,h), 64 q-rows; t-tiles of 64. Per iter: DMA tile t+1 into
//    ping, compute tile t from pong, ONE __syncthreads. QK uses kh only;
//    PV uses vh+vl. P aliases Q's LDS (wave-private rows).
//    LDS: QP 8K + 2 x 12K = 56 KB -> 2 blocks/CU.
// ---------------------------------------------------------------------------
__launch_bounds__(256)
__global__ void k_attn(const u16* __restrict__ qh_g,
                       const u16* __restrict__ kh_g,
                       const u16* __restrict__ vth_g,
                       const u16* __restrict__ vtl_g,
                       const float* __restrict__ vsum, const int* __restrict__ elen,
                       float* __restrict__ out) {
  __shared__ u16 QP[4096];        // [64][64] swizzled: Q, then P (aliased)
  __shared__ u16 Bufs[2][12288];  // per buf: Kh@0, VTh@4096, VTl@8192
  const int tid = threadIdx.x, l = tid & 63, w = tid >> 6;
  const int quad = l >> 4, col = l & 15;
  const int bh = blockIdx.x, b = bh >> 4, h = bh & 15;
  const int q0 = blockIdx.y * 64;
  const int len = elen[b];

  if (q0 >= len) {  // fully-invalid tile: uniform attention over ALL t (ref)
    float val = vsum[bh * 64 + l] * (1.0f / 1024.0f);
    float* op = out + (b * 1024 + q0) * 1024 + h * 64 + l;
    for (int r = w; r < 64; r += 4) op[r * 1024] = val;
    return;
  }

  const u16* kh_b  = kh_g + bh * 65536;
  const u16* vth_b = vth_g + bh * 65536;
  const u16* vtl_b = vtl_g + bh * 65536;

  // prologue: stage Q + tile 0
  stage64(QP, qh_g + (bh * 1024 + q0) * 64, 64, tid);
  stage64(Bufs[0], kh_b, 64, tid);
  stage64(Bufs[0] + 4096, vth_b, 1024, tid);
  stage64(Bufs[0] + 8192, vtl_b, 1024, tid);
  __syncthreads();

  short8 qf[2];  // persistent Q fragments (A-layout: m=lane&15, k=quad*8+j)
  {
    int qrow = w * 16 + col;
#pragma unroll
    for (int ks = 0; ks < 2; ks++)
      qf[ks] = *(const short8*)(QP + qrow * 64 +
                                (((ks * 4 + quad) ^ (qrow & 7)) * 8));
  }

  // fragment offsets (same swizzle for K and VT tiles)
  int kvo[2][4];
#pragma unroll
  for (int ks = 0; ks < 2; ks++)
#pragma unroll
    for (int j = 0; j < 4; j++) {
      int n = j * 16 + col;
      kvo[ks][j] = n * 64 + (((ks * 4 + quad) ^ (n & 7)) * 8);
    }
  int p_rd[2];
#pragma unroll
  for (int ks = 0; ks < 2; ks++) {
    int row = w * 16 + col;
    p_rd[ks] = row * 64 + (((ks * 4 + quad) ^ (row & 7)) * 8);
  }
  int p_wr[4][4];
#pragma unroll
  for (int r = 0; r < 4; r++) {
    int row = w * 16 + quad * 4 + r;
#pragma unroll
    for (int j = 0; j < 4; j++) {
      int cj = j * 2 + (col >> 3);
      p_wr[r][j] = row * 64 + ((cj ^ (row & 7)) * 8) + (col & 7);
    }
  }

  floatx4 zero4 = {0.f, 0.f, 0.f, 0.f};
  floatx4 O[4];
  float lp[4];  // per-thread partial l (reduced after the loop)
#pragma unroll
  for (int j = 0; j < 4; j++) O[j] = zero4;
#pragma unroll
  for (int r = 0; r < 4; r++) lp[r] = 0.f;

  const int ntt = (len + 63) >> 6;
  for (int tt = 0; tt < ntt; ++tt) {
    const int t0 = tt * 64;
    u16* cur = Bufs[tt & 1];
    if (tt + 1 < ntt) {  // overlap: DMA tile t+1 while computing tile t
      u16* nxt = Bufs[(tt + 1) & 1];
      const int t1 = t0 + 64;
      stage64(nxt, kh_b + t1 * 64, 64, tid);
      stage64(nxt + 4096, vth_b + t1, 1024, tid);
      stage64(nxt + 8192, vtl_b + t1, 1024, tid);
    }

    // ---- raw scores = Q K^T (qh * kh); q carries 0.125*log2e ----
    floatx4 sc[4];
#pragma unroll
    for (int j = 0; j < 4; j++) sc[j] = zero4;
#pragma unroll
    for (int ks = 0; ks < 2; ks++) {
#pragma unroll
      for (int j = 0; j < 4; j++) {
        short8 kbh = *(const short8*)(cur + kvo[ks][j]);
        sc[j] = MFMA(qf[ks], kbh, sc[j]);
      }
    }

    if (t0 + 64 > len) {  // wave-uniform: only the last partial tile masks
#pragma unroll
      for (int j = 0; j < 4; j++) {
        bool inv = (t0 + j * 16 + col) >= len;
#pragma unroll
        for (int r = 0; r < 4; r++)
          if (inv) sc[j][r] = -3e38f;  // exp2 -> 0
      }
    }

    // ---- static softmax weights: p = exp2(score), bf16-rounded ----
#pragma unroll
    for (int r = 0; r < 4; r++) {
#pragma unroll
      for (int j = 0; j < 4; j++) {
        float e = __builtin_exp2f(sc[j][r]);
        u16 pe = f2bf(e);
        QP[p_wr[r][j]] = pe;   // wave-private rows; no barrier needed
        lp[r] += bf2f(pe);     // l sums the weights actually used
      }
    }

    // ---- O += P * (vh + vl) ----
#pragma unroll
    for (int ks = 0; ks < 2; ks++) {
      short8 pa = *(const short8*)(QP + p_rd[ks]);
#pragma unroll
      for (int j = 0; j < 4; j++) {
        short8 vbh = *(const short8*)(cur + 4096 + kvo[ks][j]);
        short8 vbl = *(const short8*)(cur + 8192 + kvo[ks][j]);
        O[j] = MFMA(pa, vbh, O[j]);
        O[j] = MFMA(pa, vbl, O[j]);
      }
    }

    __syncthreads();  // drain next-tile DMA (overlapped) + sync compute
  }

  // ---- epilogue: reduce l, normalize; per-row override for invalid rows ----
  float l_r[4];
#pragma unroll
  for (int r = 0; r < 4; r++) l_r[r] = rowsum16(lp[r]);
#pragma unroll
  for (int r = 0; r < 4; r++) {
    int s = q0 + w * 16 + quad * 4 + r;
    float invl = 1.0f / l_r[r];
    bool valid = (s < len);
#pragma unroll
    for (int j = 0; j < 4; j++) {
      int d = j * 16 + col;
      float val = valid ? O[j][r] * invl : vsum[bh * 64 + d] * (1.0f / 1024.0f);
      out[(b * 1024 + s) * 1024 + h * 64 + d] = val;
    }
  }
}

// ---------------------------------------------------------------------------
// launch
// ---------------------------------------------------------------------------
extern "C" void kernel_launch(void* const* d_in, const int* in_sizes, int n_in,
                              void* d_out, int out_size, void* d_ws, size_t ws_size,
                              hipStream_t stream) {
  (void)in_sizes; (void)n_in; (void)out_size; (void)ws_size;
  const float* x  = (const float*)d_in[0];
  const float* Wq = (const float*)d_in[1];
  const float* bq = (const float*)d_in[2];
  const float* Wk = (const float*)d_in[3];
  const float* bk = (const float*)d_in[4];
  const float* Wv = (const float*)d_in[5];
  const float* bv = (const float*)d_in[6];
  const int* elen = (const int*)d_in[7];
  float* out = (float*)d_out;

  char* ws = (char*)d_ws;
  const size_t MB = 1024 * 1024;
  u16* xhi = (u16*)(ws + 0 * MB);
  u16* vtl = (u16*)(ws + 8 * MB);
  u16* wqh = (u16*)(ws + 16 * MB); u16* wql = (u16*)(ws + 18 * MB);
  u16* wkh = (u16*)(ws + 20 * MB); u16* wkl = (u16*)(ws + 22 * MB);
  u16* wvh = (u16*)(ws + 24 * MB); u16* wvl = (u16*)(ws + 26 * MB);
  u16* qh  = (u16*)(ws + 28 * MB);
  u16* kh  = (u16*)(ws + 36 * MB);
  u16* vth = (u16*)(ws + 44 * MB);
  float* vsum = (float*)(ws + 52 * MB);  // 4096 floats

  k_prep<<<7168, 256, 0, stream>>>(x, xhi, Wq, Wk, Wv, wqh, wql, wkh, wkl,
                                   wvh, wvl, vsum);
  k_proj<<<dim3(32, 8, 3), 256, 0, stream>>>(xhi, wqh, wql, wkh, wkl, wvh,
                                             wvl, bq, bk, bv, qh, kh, vth, vtl,
                                             vsum);
  k_attn<<<dim3(64, 16), 256, 0, stream>>>(qh, kh, vth, vtl, vsum, elen, out);
}

// Round 10
// 151.333 us; speedup vs baseline: 1.4714x; 1.2716x over previous
//
#include <hip/hip_runtime.h>
#include <stdint.h>

// ---------------------------------------------------------------------------
// MultiAttentionHead: B=4 S=1024 E=1024 H=16 D=64, fp32 in/out.
// R10: ALL-FP16 single-pass pipeline. fp16 (11 mantissa bits) matches the
// accuracy of the old 2-pass bf16 hi/lo scheme (err std ~6e-4 either way)
// at HALF the MFMAs and 2/3 the staging. All ranges fit fp16 comfortably.
// Attention: QK = q*k (q pre-scaled 0.125*log2e), static softmax p=exp2(s)
// (f16-rounded; l sums the rounded p), PV = p*v. Rows s >= len[b] get
// uniform attention = mean(V) via vsum (fp32, from projection accs).
// Carried: R1 XOR swizzle (0 conflicts), R4 static softmax, R7 k_attn dbuf
// (1 barrier/iter), R8 LDS-staged epilogue (WRITE 61->33 MB confirmed) +
// direct V^T + fused prep. R9 post-mortem: k_proj BK=32 dbuf REGRESSED
// (compute/iter 155 cyc << 900 cyc latency) -> k_proj keeps BK=64 2-barrier.
// ---------------------------------------------------------------------------

using u16     = unsigned short;
using half8   = __attribute__((ext_vector_type(8))) _Float16;
using floatx4 = __attribute__((ext_vector_type(4))) float;

#define MFMA16(a, b, c) __builtin_amdgcn_mfma_f32_16x16x32_f16(a, b, c, 0, 0, 0)

__device__ __forceinline__ u16 f2h(float f) {  // f32 -> f16 bits (RTN)
  _Float16 h = (_Float16)f; u16 u; __builtin_memcpy(&u, &h, 2); return u;
}
__device__ __forceinline__ float h2f(u16 u) {
  _Float16 h; __builtin_memcpy(&h, &u, 2); return (float)h;
}

// DPP rotate within aligned 16-lane rows (pure VALU; no LDS pipe).
template <int CTRL>
__device__ __forceinline__ float dppf(float v) {
  return __int_as_float(__builtin_amdgcn_update_dpp(
      0, __float_as_int(v), CTRL, 0xF, 0xF, true));
}
__device__ __forceinline__ float rowsum16(float v) {  // all-reduce sum, 16 lanes
  v += dppf<0x121>(v);
  v += dppf<0x122>(v);
  v += dppf<0x124>(v);
  v += dppf<0x128>(v);
  return v;
}

// async global->LDS DMA, 16B per lane. LDS dest must be wave-uniform base +
// lane*16 (no per-lane scatter) -- so bank swizzles permute the GLOBAL src.
__device__ __forceinline__ void async_cp16(void* lds, const void* g) {
  __builtin_amdgcn_global_load_lds(
      (__attribute__((address_space(1))) uint32_t*)(uintptr_t)g,
      (__attribute__((address_space(3))) uint32_t*)(uint32_t)(uintptr_t)lds,
      16, 0, 0);
}

// ---------------------------------------------------------------------------
// 1) prep (fused): blocks [0,4096): x -> f16 (block 0 zeroes vsum);
//    blocks [4096,7168): transpose W -> WT[n][k] f16.
// ---------------------------------------------------------------------------
__global__ void k_prep(const float* __restrict__ x, u16* __restrict__ xh,
                       const float* __restrict__ w0, const float* __restrict__ w1,
                       const float* __restrict__ w2,
                       u16* __restrict__ o0, u16* __restrict__ o1,
                       u16* __restrict__ o2, float* __restrict__ vsum) {
  __shared__ float t[32][33];
  const int bx = blockIdx.x;
  if (bx < 4096) {
    int i = (bx * 256 + threadIdx.x) * 4;
    float4 v = *(const float4*)(x + i);
    ushort4 hv;
    hv.x = f2h(v.x);
    hv.y = f2h(v.y);
    hv.z = f2h(v.z);
    hv.w = f2h(v.w);
    *(ushort4*)(xh + i) = hv;
    if (bx == 0) {  // zero vsum (4096 floats) for k_proj's atomics
      float4 z = {0.f, 0.f, 0.f, 0.f};
#pragma unroll
      for (int e = 0; e < 4; e++) ((float4*)vsum)[threadIdx.x * 4 + e] = z;
    }
    return;
  }
  const int id = bx - 4096;                 // 0..3071
  const int z = id >> 10, rem = id & 1023;
  const float* W = z == 0 ? w0 : (z == 1 ? w1 : w2);
  u16* oh = z == 0 ? o0 : (z == 1 ? o1 : o2);
  const int kb = (rem & 31) * 32, nb = (rem >> 5) * 32;
  const int tx = threadIdx.x & 31, ty = threadIdx.x >> 5;
  for (int r = ty; r < 32; r += 8) t[r][tx] = W[(kb + r) * 1024 + nb + tx];
  __syncthreads();
  for (int r = ty; r < 32; r += 8)
    oh[(nb + r) * 1024 + kb + tx] = f2h(t[tx][r]);
}

// ---------------------------------------------------------------------------
// 2) projection GEMM: C[4096][1024] = xh @ Wh + b, fp16 single pass,
//    128x128 tile, BK=64, 2-barrier K-loop (R9 showed dbuf regresses here).
//    LDS 32 KB staging (A + B [128][64] f16, 8-chunk XOR swizzle) /
//    34.8 KB epilogue tile -> 4 blocks/CU. Epilogue stages C through LDS
//    ([128][136]) for 16B stores. z=0/1 -> q/k f16 in [B][H][S][D] (q
//    pre-scaled by 0.125*log2e); z=2 -> V^T f16 in [B][H][D][S] + vsum.
// ---------------------------------------------------------------------------
__launch_bounds__(256, 4)
__global__ void k_proj(const u16* __restrict__ xh,
                       const u16* __restrict__ wqT, const u16* __restrict__ wkT,
                       const u16* __restrict__ wvT,
                       const float* __restrict__ bq, const float* __restrict__ bk,
                       const float* __restrict__ bv,
                       u16* __restrict__ qh, u16* __restrict__ kh,
                       u16* __restrict__ vth, float* __restrict__ vsum) {
  __shared__ u16 Sm[17408];  // K-loop: A@0, B@8192 ([128][64] f16 = 16 KB ea);
                             // epilogue: C tile [128][136] (34816 B)
  const int z = blockIdx.z;
  const u16* wT = z == 0 ? wqT : (z == 1 ? wkT : wvT);
  const float* bias = z == 0 ? bq : (z == 1 ? bk : bv);
  u16* oh = z == 0 ? qh : (z == 1 ? kh : vth);
  const float oscale = (z == 0) ? 0.18033688011112042f : 1.0f;  // 0.125*log2(e)

  const int tid = threadIdx.x, l = tid & 63, w = tid >> 6;
  const int quad = l >> 4, col = l & 15;
  const int m0 = blockIdx.x * 128, n0 = blockIdx.y * 128;
  const int wm = (w & 1) * 64, wn = (w >> 1) * 64;

  // staging: thread covers slots {tid, tid+256, tid+512, tid+768} (x8 elems)
  // per tile; src chunk = ch ^ (row&7) ((row+32p)&7 invariant).
  const int row0 = tid >> 3, ch = tid & 7;
  const int sc8 = (ch ^ (row0 & 7)) * 8;
  int gofs[4], lofs[4];
#pragma unroll
  for (int p = 0; p < 4; p++) {
    gofs[p] = (row0 + 32 * p) * 1024 + sc8;
    lofs[p] = (tid + p * 256) * 8;
  }

  const u16* Ag = xh + m0 * 1024;
  const u16* Bg = wT + n0 * 1024;

  // fragment LDS offsets: logical chunk c = ks*4+quad stored at c^(r&7)
  int ar[2][4], br[2][4];
#pragma unroll
  for (int ks = 0; ks < 2; ks++) {
#pragma unroll
    for (int i = 0; i < 4; i++) {
      int r = wm + i * 16 + col;
      ar[ks][i] = r * 64 + (((ks * 4 + quad) ^ (r & 7)) * 8);
    }
#pragma unroll
    for (int j = 0; j < 4; j++) {
      int r = wn + j * 16 + col;
      br[ks][j] = r * 64 + (((ks * 4 + quad) ^ (r & 7)) * 8);
    }
  }

  floatx4 zero4 = {0.f, 0.f, 0.f, 0.f};
  floatx4 acc[4][4];
#pragma unroll
  for (int i = 0; i < 4; i++)
#pragma unroll
    for (int j = 0; j < 4; j++) acc[i][j] = zero4;

  for (int k0 = 0; k0 < 1024; k0 += 64) {
    __syncthreads();  // previous compute done before LDS overwrite
#pragma unroll
    for (int p = 0; p < 4; p++) async_cp16(Sm + lofs[p], Ag + gofs[p] + k0);
#pragma unroll
    for (int p = 0; p < 4; p++)
      async_cp16(Sm + 8192 + lofs[p], Bg + gofs[p] + k0);
    __syncthreads();  // DMA drained

#pragma unroll
    for (int ks = 0; ks < 2; ks++) {
      half8 fa[4], fb[4];
#pragma unroll
      for (int i = 0; i < 4; i++) fa[i] = *(const half8*)(Sm + ar[ks][i]);
#pragma unroll
      for (int j = 0; j < 4; j++)
        fb[j] = *(const half8*)(Sm + 8192 + br[ks][j]);
#pragma unroll
      for (int i = 0; i < 4; i++)
#pragma unroll
        for (int j = 0; j < 4; j++) acc[i][j] = MFMA16(fa[i], fb[j], acc[i][j]);
    }
  }

  // ---- epilogue: stage C tile in LDS ([128][136]) for coalesced stores ----
  const int bidx = m0 >> 10;     // batch index
  const int sbase = m0 & 1023;
  __syncthreads();  // all K-loop LDS reads done before overwrite

#pragma unroll
  for (int j = 0; j < 4; j++) {
    int nloc = wn + j * 16 + col;
    float bb = bias[n0 + nloc];
#pragma unroll
    for (int i = 0; i < 4; i++)
#pragma unroll
      for (int r = 0; r < 4; r++) {
        int mloc = wm + i * 16 + quad * 4 + r;
        Sm[mloc * 136 + nloc] = f2h((acc[i][j][r] + bb) * oscale);
      }
  }
  __syncthreads();

  if (z != 2) {
    // q/k: [bh][s][64] -- row-contiguous 16B chunks
#pragma unroll
    for (int k = 0; k < 8; k++) {
      int c = tid + k * 256;
      int mloc = c >> 4, n = (c & 15) * 8;
      int hh = (n0 + n) >> 6, d = (n0 + n) & 63;
      half8 vv = *(const half8*)(Sm + mloc * 136 + n);
      *(half8*)(oh + ((bidx * 16 + hh) * 1024 + sbase + mloc) * 64 + d) = vv;
    }
  } else {
    // V^T: [bh][d][1024] -- transposed read, s-contiguous 16B stores
#pragma unroll
    for (int k = 0; k < 8; k++) {
      int c = tid + k * 256;
      int nloc = c & 127, s0 = (c >> 7) * 8;
      int hh = (n0 + nloc) >> 6, d = (n0 + nloc) & 63;
      u16 tmp[8];
#pragma unroll
      for (int e = 0; e < 8; e++) tmp[e] = Sm[(s0 + e) * 136 + nloc];
      *(half8*)(vth + ((bidx * 16 + hh) * 64 + d) * 1024 + sbase + s0) =
          *(half8*)tmp;
    }
    // vsum partials from fp32 acc: vsum[bh*64+d] += sum over this block's s
#pragma unroll
    for (int j = 0; j < 4; j++) {
      int nloc = wn + j * 16 + col;
      float bb = bias[n0 + nloc];
      float part = 16.0f * bb;
#pragma unroll
      for (int i = 0; i < 4; i++)
#pragma unroll
        for (int r = 0; r < 4; r++) part += acc[i][j][r];
      part += __shfl_xor(part, 16, 64);  // reduce across quads (same n)
      part += __shfl_xor(part, 32, 64);
      if (quad == 0) {
        int hh = (n0 + nloc) >> 6, d = (n0 + nloc) & 63;
        unsafeAtomicAdd(vsum + (bidx * 16 + hh) * 64 + d, part);
      }
    }
  }
}

// ---------------------------------------------------------------------------
// Swizzled 64x64 f16 tile stage (global -> LDS via DMA).
// ---------------------------------------------------------------------------
__device__ __forceinline__ void stage64(u16* lds, const u16* g, int row_stride,
                                        int tid) {
#pragma unroll
  for (int p = 0; p < 2; p++) {
    int slot = (p * 256 + tid) * 8;  // element index; *2 = bytes
    int row = slot >> 6;
    int gp = (slot >> 3) & 7;
    int gl = gp ^ (row & 7);
    async_cp16(lds + slot, g + row * row_stride + gl * 8);
  }
}

// ---------------------------------------------------------------------------
// 3) flash attention, fp16, static softmax, double-buffered staging.
//    Block: one (b,h), 64 q-rows; t-tiles of 64. Per iter: DMA tile t+1 into
//    ping, compute tile t from pong, ONE __syncthreads. QK: 8 MFMA, PV: 8.
//    P (f16) aliases Q's LDS (wave-private rows). LDS: QP 8K + 2 x 16K =
//    40960 B -> EXACTLY 4 blocks/CU.
// ---------------------------------------------------------------------------
__launch_bounds__(256)
__global__ void k_attn(const u16* __restrict__ qh_g,
                       const u16* __restrict__ kh_g,
                       const u16* __restrict__ vth_g,
                       const float* __restrict__ vsum, const int* __restrict__ elen,
                       float* __restrict__ out) {
  __shared__ u16 QP[4096];       // [64][64] swizzled: Q, then P (aliased)
  __shared__ u16 Bufs[2][8192];  // per buf: K@0, VT@4096 ([64][64] swizzled)
  const int tid = threadIdx.x, l = tid & 63, w = tid >> 6;
  const int quad = l >> 4, col = l & 15;
  const int bh = blockIdx.x, b = bh >> 4, h = bh & 15;
  const int q0 = blockIdx.y * 64;
  const int len = elen[b];

  if (q0 >= len) {  // fully-invalid tile: uniform attention over ALL t (ref)
    float val = vsum[bh * 64 + l] * (1.0f / 1024.0f);
    float* op = out + (b * 1024 + q0) * 1024 + h * 64 + l;
    for (int r = w; r < 64; r += 4) op[r * 1024] = val;
    return;
  }

  const u16* kh_b  = kh_g + bh * 65536;
  const u16* vth_b = vth_g + bh * 65536;

  // prologue: stage Q + tile 0
  stage64(QP, qh_g + (bh * 1024 + q0) * 64, 64, tid);
  stage64(Bufs[0], kh_b, 64, tid);
  stage64(Bufs[0] + 4096, vth_b, 1024, tid);
  __syncthreads();

  half8 qf[2];  // persistent Q fragments (A-layout: m=lane&15, k=quad*8+j)
  {
    int qrow = w * 16 + col;
#pragma unroll
    for (int ks = 0; ks < 2; ks++)
      qf[ks] = *(const half8*)(QP + qrow * 64 +
                               (((ks * 4 + quad) ^ (qrow & 7)) * 8));
  }

  // fragment offsets (same swizzle for K and VT tiles)
  int kvo[2][4];
#pragma unroll
  for (int ks = 0; ks < 2; ks++)
#pragma unroll
    for (int j = 0; j < 4; j++) {
      int n = j * 16 + col;
      kvo[ks][j] = n * 64 + (((ks * 4 + quad) ^ (n & 7)) * 8);
    }
  int p_rd[2];
#pragma unroll
  for (int ks = 0; ks < 2; ks++) {
    int row = w * 16 + col;
    p_rd[ks] = row * 64 + (((ks * 4 + quad) ^ (row & 7)) * 8);
  }
  int p_wr[4][4];
#pragma unroll
  for (int r = 0; r < 4; r++) {
    int row = w * 16 + quad * 4 + r;
#pragma unroll
    for (int j = 0; j < 4; j++) {
      int cj = j * 2 + (col >> 3);
      p_wr[r][j] = row * 64 + ((cj ^ (row & 7)) * 8) + (col & 7);
    }
  }

  floatx4 zero4 = {0.f, 0.f, 0.f, 0.f};
  floatx4 O[4];
  float lp[4];  // per-thread partial l (reduced after the loop)
#pragma unroll
  for (int j = 0; j < 4; j++) O[j] = zero4;
#pragma unroll
  for (int r = 0; r < 4; r++) lp[r] = 0.f;

  const int ntt = (len + 63) >> 6;
  for (int tt = 0; tt < ntt; ++tt) {
    const int t0 = tt * 64;
    u16* cur = Bufs[tt & 1];
    if (tt + 1 < ntt) {  // overlap: DMA tile t+1 while computing tile t
      u16* nxt = Bufs[(tt + 1) & 1];
      const int t1 = t0 + 64;
      stage64(nxt, kh_b + t1 * 64, 64, tid);
      stage64(nxt + 4096, vth_b + t1, 1024, tid);
    }

    // ---- raw scores = Q K^T; q carries 0.125*log2e ----
    floatx4 sc[4];
#pragma unroll
    for (int j = 0; j < 4; j++) sc[j] = zero4;
#pragma unroll
    for (int ks = 0; ks < 2; ks++) {
#pragma unroll
      for (int j = 0; j < 4; j++) {
        half8 kb = *(const half8*)(cur + kvo[ks][j]);
        sc[j] = MFMA16(qf[ks], kb, sc[j]);
      }
    }

    if (t0 + 64 > len) {  // wave-uniform: only the last partial tile masks
#pragma unroll
      for (int j = 0; j < 4; j++) {
        bool inv = (t0 + j * 16 + col) >= len;
#pragma unroll
        for (int r = 0; r < 4; r++)
          if (inv) sc[j][r] = -3e38f;  // exp2 -> 0
      }
    }

    // ---- static softmax weights: p = exp2(score), f16-rounded ----
#pragma unroll
    for (int r = 0; r < 4; r++) {
#pragma unroll
      for (int j = 0; j < 4; j++) {
        float e = __builtin_exp2f(sc[j][r]);
        u16 pe = f2h(e);
        QP[p_wr[r][j]] = pe;   // wave-private rows; no barrier needed
        lp[r] += h2f(pe);      // l sums the weights actually used
      }
    }

    // ---- O += P * V ----
#pragma unroll
    for (int ks = 0; ks < 2; ks++) {
      half8 pa = *(const half8*)(QP + p_rd[ks]);
#pragma unroll
      for (int j = 0; j < 4; j++) {
        half8 vb = *(const half8*)(cur + 4096 + kvo[ks][j]);
        O[j] = MFMA16(pa, vb, O[j]);
      }
    }

    __syncthreads();  // drain next-tile DMA (overlapped) + sync compute
  }

  // ---- epilogue: reduce l, normalize; per-row override for invalid rows ----
  float l_r[4];
#pragma unroll
  for (int r = 0; r < 4; r++) l_r[r] = rowsum16(lp[r]);
#pragma unroll
  for (int r = 0; r < 4; r++) {
    int s = q0 + w * 16 + quad * 4 + r;
    float invl = 1.0f / l_r[r];
    bool valid = (s < len);
#pragma unroll
    for (int j = 0; j < 4; j++) {
      int d = j * 16 + col;
      float val = valid ? O[j][r] * invl : vsum[bh * 64 + d] * (1.0f / 1024.0f);
      out[(b * 1024 + s) * 1024 + h * 64 + d] = val;
    }
  }
}

// ---------------------------------------------------------------------------
// launch
// ---------------------------------------------------------------------------
extern "C" void kernel_launch(void* const* d_in, const int* in_sizes, int n_in,
                              void* d_out, int out_size, void* d_ws, size_t ws_size,
                              hipStream_t stream) {
  (void)in_sizes; (void)n_in; (void)out_size; (void)ws_size;
  const float* x  = (const float*)d_in[0];
  const float* Wq = (const float*)d_in[1];
  const float* bq = (const float*)d_in[2];
  const float* Wk = (const float*)d_in[3];
  const float* bk = (const float*)d_in[4];
  const float* Wv = (const float*)d_in[5];
  const float* bv = (const float*)d_in[6];
  const int* elen = (const int*)d_in[7];
  float* out = (float*)d_out;

  char* ws = (char*)d_ws;
  const size_t MB = 1024 * 1024;
  u16* xh  = (u16*)(ws + 0 * MB);
  u16* wqT = (u16*)(ws + 8 * MB);
  u16* wkT = (u16*)(ws + 10 * MB);
  u16* wvT = (u16*)(ws + 12 * MB);
  u16* qh  = (u16*)(ws + 14 * MB);
  u16* kh  = (u16*)(ws + 22 * MB);
  u16* vth = (u16*)(ws + 30 * MB);
  float* vsum = (float*)(ws + 38 * MB);  // 4096 floats

  k_prep<<<7168, 256, 0, stream>>>(x, xh, Wq, Wk, Wv, wqT, wkT, wvT, vsum);
  k_proj<<<dim3(32, 8, 3), 256, 0, stream>>>(xh, wqT, wkT, wvT, bq, bk, bv,
                                             qh, kh, vth, vsum);
  k_attn<<<dim3(64, 16), 256, 0, stream>>>(qh, kh, vth, vsum, elen, out);
}

// Round 11
// 148.877 us; speedup vs baseline: 1.4956x; 1.0165x over previous
//
#include <hip/hip_runtime.h>
#include <stdint.h>

// ---------------------------------------------------------------------------
// MultiAttentionHead: B=4 S=1024 E=1024 H=16 D=64, fp32 in/out.
// R10: ALL-FP16 single-pass pipeline (matched 2-pass bf16 accuracy at half
// the MFMAs). R11: k_attn BLOCK-INDEX REMAP -- grid was (bh, qtile) so each
// CU's 4 resident blocks shared one batch/len (stride-256 same-x); short-len
// CUs idled while longest-batch CUs serialized 64 t-iters. New 1-D id map
// b=(id+(id>>8))&3 puts all 4 batches on every CU -> balanced ~Sigma(n_b)
// iters/CU. Also: l sums unrounded e (drops 16 h2f cvts/iter).
// Attention: QK = q*k (q pre-scaled 0.125*log2e), static softmax p=exp2(s)
// (f16-rounded for PV), PV = p*v. Rows s >= len[b]: uniform attn = mean(V).
// Carried: R1 XOR swizzle (0 conflicts), R4 static softmax, R7 k_attn dbuf
// (1 barrier/iter), R8 LDS-staged epilogue + direct V^T + fused prep.
// R9 post-mortem: k_proj BK=32 dbuf regressed -> keeps BK=64 2-barrier.
// ---------------------------------------------------------------------------

using u16     = unsigned short;
using half8   = __attribute__((ext_vector_type(8))) _Float16;
using floatx4 = __attribute__((ext_vector_type(4))) float;

#define MFMA16(a, b, c) __builtin_amdgcn_mfma_f32_16x16x32_f16(a, b, c, 0, 0, 0)

__device__ __forceinline__ u16 f2h(float f) {  // f32 -> f16 bits (RTN)
  _Float16 h = (_Float16)f; u16 u; __builtin_memcpy(&u, &h, 2); return u;
}

// DPP rotate within aligned 16-lane rows (pure VALU; no LDS pipe).
template <int CTRL>
__device__ __forceinline__ float dppf(float v) {
  return __int_as_float(__builtin_amdgcn_update_dpp(
      0, __float_as_int(v), CTRL, 0xF, 0xF, true));
}
__device__ __forceinline__ float rowsum16(float v) {  // all-reduce sum, 16 lanes
  v += dppf<0x121>(v);
  v += dppf<0x122>(v);
  v += dppf<0x124>(v);
  v += dppf<0x128>(v);
  return v;
}

// async global->LDS DMA, 16B per lane. LDS dest must be wave-uniform base +
// lane*16 (no per-lane scatter) -- so bank swizzles permute the GLOBAL src.
__device__ __forceinline__ void async_cp16(void* lds, const void* g) {
  __builtin_amdgcn_global_load_lds(
      (__attribute__((address_space(1))) uint32_t*)(uintptr_t)g,
      (__attribute__((address_space(3))) uint32_t*)(uint32_t)(uintptr_t)lds,
      16, 0, 0);
}

// ---------------------------------------------------------------------------
// 1) prep (fused): blocks [0,4096): x -> f16 (block 0 zeroes vsum);
//    blocks [4096,7168): transpose W -> WT[n][k] f16.
// ---------------------------------------------------------------------------
__global__ void k_prep(const float* __restrict__ x, u16* __restrict__ xh,
                       const float* __restrict__ w0, const float* __restrict__ w1,
                       const float* __restrict__ w2,
                       u16* __restrict__ o0, u16* __restrict__ o1,
                       u16* __restrict__ o2, float* __restrict__ vsum) {
  __shared__ float t[32][33];
  const int bx = blockIdx.x;
  if (bx < 4096) {
    int i = (bx * 256 + threadIdx.x) * 4;
    float4 v = *(const float4*)(x + i);
    ushort4 hv;
    hv.x = f2h(v.x);
    hv.y = f2h(v.y);
    hv.z = f2h(v.z);
    hv.w = f2h(v.w);
    *(ushort4*)(xh + i) = hv;
    if (bx == 0) {  // zero vsum (4096 floats) for k_proj's atomics
      float4 z = {0.f, 0.f, 0.f, 0.f};
#pragma unroll
      for (int e = 0; e < 4; e++) ((float4*)vsum)[threadIdx.x * 4 + e] = z;
    }
    return;
  }
  const int id = bx - 4096;                 // 0..3071
  const int z = id >> 10, rem = id & 1023;
  const float* W = z == 0 ? w0 : (z == 1 ? w1 : w2);
  u16* oh = z == 0 ? o0 : (z == 1 ? o1 : o2);
  const int kb = (rem & 31) * 32, nb = (rem >> 5) * 32;
  const int tx = threadIdx.x & 31, ty = threadIdx.x >> 5;
  for (int r = ty; r < 32; r += 8) t[r][tx] = W[(kb + r) * 1024 + nb + tx];
  __syncthreads();
  for (int r = ty; r < 32; r += 8)
    oh[(nb + r) * 1024 + kb + tx] = f2h(t[tx][r]);
}

// ---------------------------------------------------------------------------
// 2) projection GEMM: C[4096][1024] = xh @ Wh + b, fp16 single pass,
//    128x128 tile, BK=64, 2-barrier K-loop (R9: dbuf regresses here).
//    LDS 32 KB staging / 34.8 KB epilogue tile -> 4 blocks/CU. Epilogue
//    stages C through LDS ([128][136]) for 16B stores. z=0/1 -> q/k f16 in
//    [B][H][S][D] (q pre-scaled by 0.125*log2e); z=2 -> V^T f16 + vsum.
// ---------------------------------------------------------------------------
__launch_bounds__(256, 4)
__global__ void k_proj(const u16* __restrict__ xh,
                       const u16* __restrict__ wqT, const u16* __restrict__ wkT,
                       const u16* __restrict__ wvT,
                       const float* __restrict__ bq, const float* __restrict__ bk,
                       const float* __restrict__ bv,
                       u16* __restrict__ qh, u16* __restrict__ kh,
                       u16* __restrict__ vth, float* __restrict__ vsum) {
  __shared__ u16 Sm[17408];  // K-loop: A@0, B@8192 ([128][64] f16 = 16 KB ea);
                             // epilogue: C tile [128][136] (34816 B)
  const int z = blockIdx.z;
  const u16* wT = z == 0 ? wqT : (z == 1 ? wkT : wvT);
  const float* bias = z == 0 ? bq : (z == 1 ? bk : bv);
  u16* oh = z == 0 ? qh : (z == 1 ? kh : vth);
  const float oscale = (z == 0) ? 0.18033688011112042f : 1.0f;  // 0.125*log2(e)

  const int tid = threadIdx.x, l = tid & 63, w = tid >> 6;
  const int quad = l >> 4, col = l & 15;
  const int m0 = blockIdx.x * 128, n0 = blockIdx.y * 128;
  const int wm = (w & 1) * 64, wn = (w >> 1) * 64;

  const int row0 = tid >> 3, ch = tid & 7;
  const int sc8 = (ch ^ (row0 & 7)) * 8;
  int gofs[4], lofs[4];
#pragma unroll
  for (int p = 0; p < 4; p++) {
    gofs[p] = (row0 + 32 * p) * 1024 + sc8;
    lofs[p] = (tid + p * 256) * 8;
  }

  const u16* Ag = xh + m0 * 1024;
  const u16* Bg = wT + n0 * 1024;

  int ar[2][4], br[2][4];
#pragma unroll
  for (int ks = 0; ks < 2; ks++) {
#pragma unroll
    for (int i = 0; i < 4; i++) {
      int r = wm + i * 16 + col;
      ar[ks][i] = r * 64 + (((ks * 4 + quad) ^ (r & 7)) * 8);
    }
#pragma unroll
    for (int j = 0; j < 4; j++) {
      int r = wn + j * 16 + col;
      br[ks][j] = r * 64 + (((ks * 4 + quad) ^ (r & 7)) * 8);
    }
  }

  floatx4 zero4 = {0.f, 0.f, 0.f, 0.f};
  floatx4 acc[4][4];
#pragma unroll
  for (int i = 0; i < 4; i++)
#pragma unroll
    for (int j = 0; j < 4; j++) acc[i][j] = zero4;

  for (int k0 = 0; k0 < 1024; k0 += 64) {
    __syncthreads();  // previous compute done before LDS overwrite
#pragma unroll
    for (int p = 0; p < 4; p++) async_cp16(Sm + lofs[p], Ag + gofs[p] + k0);
#pragma unroll
    for (int p = 0; p < 4; p++)
      async_cp16(Sm + 8192 + lofs[p], Bg + gofs[p] + k0);
    __syncthreads();  // DMA drained

#pragma unroll
    for (int ks = 0; ks < 2; ks++) {
      half8 fa[4], fb[4];
#pragma unroll
      for (int i = 0; i < 4; i++) fa[i] = *(const half8*)(Sm + ar[ks][i]);
#pragma unroll
      for (int j = 0; j < 4; j++)
        fb[j] = *(const half8*)(Sm + 8192 + br[ks][j]);
#pragma unroll
      for (int i = 0; i < 4; i++)
#pragma unroll
        for (int j = 0; j < 4; j++) acc[i][j] = MFMA16(fa[i], fb[j], acc[i][j]);
    }
  }

  // ---- epilogue: stage C tile in LDS ([128][136]) for coalesced stores ----
  const int bidx = m0 >> 10;     // batch index
  const int sbase = m0 & 1023;
  __syncthreads();  // all K-loop LDS reads done before overwrite

#pragma unroll
  for (int j = 0; j < 4; j++) {
    int nloc = wn + j * 16 + col;
    float bb = bias[n0 + nloc];
#pragma unroll
    for (int i = 0; i < 4; i++)
#pragma unroll
      for (int r = 0; r < 4; r++) {
        int mloc = wm + i * 16 + quad * 4 + r;
        Sm[mloc * 136 + nloc] = f2h((acc[i][j][r] + bb) * oscale);
      }
  }
  __syncthreads();

  if (z != 2) {
    // q/k: [bh][s][64] -- row-contiguous 16B chunks
#pragma unroll
    for (int k = 0; k < 8; k++) {
      int c = tid + k * 256;
      int mloc = c >> 4, n = (c & 15) * 8;
      int hh = (n0 + n) >> 6, d = (n0 + n) & 63;
      half8 vv = *(const half8*)(Sm + mloc * 136 + n);
      *(half8*)(oh + ((bidx * 16 + hh) * 1024 + sbase + mloc) * 64 + d) = vv;
    }
  } else {
    // V^T: [bh][d][1024] -- transposed read, s-contiguous 16B stores
#pragma unroll
    for (int k = 0; k < 8; k++) {
      int c = tid + k * 256;
      int nloc = c & 127, s0 = (c >> 7) * 8;
      int hh = (n0 + nloc) >> 6, d = (n0 + nloc) & 63;
      u16 tmp[8];
#pragma unroll
      for (int e = 0; e < 8; e++) tmp[e] = Sm[(s0 + e) * 136 + nloc];
      *(half8*)(vth + ((bidx * 16 + hh) * 64 + d) * 1024 + sbase + s0) =
          *(half8*)tmp;
    }
    // vsum partials from fp32 acc: vsum[bh*64+d] += sum over this block's s
#pragma unroll
    for (int j = 0; j < 4; j++) {
      int nloc = wn + j * 16 + col;
      float bb = bias[n0 + nloc];
      float part = 16.0f * bb;
#pragma unroll
      for (int i = 0; i < 4; i++)
#pragma unroll
        for (int r = 0; r < 4; r++) part += acc[i][j][r];
      part += __shfl_xor(part, 16, 64);  // reduce across quads (same n)
      part += __shfl_xor(part, 32, 64);
      if (quad == 0) {
        int hh = (n0 + nloc) >> 6, d = (n0 + nloc) & 63;
        unsafeAtomicAdd(vsum + (bidx * 16 + hh) * 64 + d, part);
      }
    }
  }
}

// ---------------------------------------------------------------------------
// Swizzled 64x64 f16 tile stage (global -> LDS via DMA).
// ---------------------------------------------------------------------------
__device__ __forceinline__ void stage64(u16* lds, const u16* g, int row_stride,
                                        int tid) {
#pragma unroll
  for (int p = 0; p < 2; p++) {
    int slot = (p * 256 + tid) * 8;  // element index; *2 = bytes
    int row = slot >> 6;
    int gp = (slot >> 3) & 7;
    int gl = gp ^ (row & 7);
    async_cp16(lds + slot, g + row * row_stride + gl * 8);
  }
}

// ---------------------------------------------------------------------------
// 3) flash attention, fp16, static softmax, double-buffered staging.
//    1-D grid of 1024, id remapped so each CU's 4 resident blocks span ALL
//    4 batches (b = (id + id>>8) & 3): with stride-256 residency this
//    balances per-CU work at ~Sigma(ceil(len_b/64)) t-iters (R11).
//    Per iter: DMA tile t+1 into ping, compute tile t from pong, ONE
//    __syncthreads. P (f16) aliases Q's LDS. LDS 40960 B -> 4 blocks/CU.
// ---------------------------------------------------------------------------
__launch_bounds__(256)
__global__ void k_attn(const u16* __restrict__ qh_g,
                       const u16* __restrict__ kh_g,
                       const u16* __restrict__ vth_g,
                       const float* __restrict__ vsum, const int* __restrict__ elen,
                       float* __restrict__ out) {
  __shared__ u16 QP[4096];       // [64][64] swizzled: Q, then P (aliased)
  __shared__ u16 Bufs[2][8192];  // per buf: K@0, VT@4096 ([64][64] swizzled)
  const int tid = threadIdx.x, l = tid & 63, w = tid >> 6;
  const int quad = l >> 4, col = l & 15;
  // ---- R11 balance remap (bijective): each CU's {id, id+256, id+512,
  //      id+768} resident set cycles through all 4 batches ----
  const int id = blockIdx.x;
  const int b = (id + (id >> 8)) & 3;
  const int h = (id >> 2) & 15;
  const int bh = b * 16 + h;
  const int q0 = ((id >> 6) & 15) * 64;
  const int len = elen[b];

  if (q0 >= len) {  // fully-invalid tile: uniform attention over ALL t (ref)
    float val = vsum[bh * 64 + l] * (1.0f / 1024.0f);
    float* op = out + (b * 1024 + q0) * 1024 + h * 64 + l;
    for (int r = w; r < 64; r += 4) op[r * 1024] = val;
    return;
  }

  const u16* kh_b  = kh_g + bh * 65536;
  const u16* vth_b = vth_g + bh * 65536;

  // prologue: stage Q + tile 0
  stage64(QP, qh_g + (bh * 1024 + q0) * 64, 64, tid);
  stage64(Bufs[0], kh_b, 64, tid);
  stage64(Bufs[0] + 4096, vth_b, 1024, tid);
  __syncthreads();

  half8 qf[2];  // persistent Q fragments (A-layout: m=lane&15, k=quad*8+j)
  {
    int qrow = w * 16 + col;
#pragma unroll
    for (int ks = 0; ks < 2; ks++)
      qf[ks] = *(const half8*)(QP + qrow * 64 +
                               (((ks * 4 + quad) ^ (qrow & 7)) * 8));
  }

  // fragment offsets (same swizzle for K and VT tiles)
  int kvo[2][4];
#pragma unroll
  for (int ks = 0; ks < 2; ks++)
#pragma unroll
    for (int j = 0; j < 4; j++) {
      int n = j * 16 + col;
      kvo[ks][j] = n * 64 + (((ks * 4 + quad) ^ (n & 7)) * 8);
    }
  int p_rd[2];
#pragma unroll
  for (int ks = 0; ks < 2; ks++) {
    int row = w * 16 + col;
    p_rd[ks] = row * 64 + (((ks * 4 + quad) ^ (row & 7)) * 8);
  }
  int p_wr[4][4];
#pragma unroll
  for (int r = 0; r < 4; r++) {
    int row = w * 16 + quad * 4 + r;
#pragma unroll
    for (int j = 0; j < 4; j++) {
      int cj = j * 2 + (col >> 3);
      p_wr[r][j] = row * 64 + ((cj ^ (row & 7)) * 8) + (col & 7);
    }
  }

  floatx4 zero4 = {0.f, 0.f, 0.f, 0.f};
  floatx4 O[4];
  float lp[4];  // per-thread partial l (reduced after the loop)
#pragma unroll
  for (int j = 0; j < 4; j++) O[j] = zero4;
#pragma unroll
  for (int r = 0; r < 4; r++) lp[r] = 0.f;

  const int ntt = (len + 63) >> 6;
  for (int tt = 0; tt < ntt; ++tt) {
    const int t0 = tt * 64;
    u16* cur = Bufs[tt & 1];
    if (tt + 1 < ntt) {  // overlap: DMA tile t+1 while computing tile t
      u16* nxt = Bufs[(tt + 1) & 1];
      const int t1 = t0 + 64;
      stage64(nxt, kh_b + t1 * 64, 64, tid);
      stage64(nxt + 4096, vth_b + t1, 1024, tid);
    }

    // ---- raw scores = Q K^T; q carries 0.125*log2e ----
    floatx4 sc[4];
#pragma unroll
    for (int j = 0; j < 4; j++) sc[j] = zero4;
#pragma unroll
    for (int ks = 0; ks < 2; ks++) {
#pragma unroll
      for (int j = 0; j < 4; j++) {
        half8 kb = *(const half8*)(cur + kvo[ks][j]);
        sc[j] = MFMA16(qf[ks], kb, sc[j]);
      }
    }

    if (t0 + 64 > len) {  // wave-uniform: only the last partial tile masks
#pragma unroll
      for (int j = 0; j < 4; j++) {
        bool inv = (t0 + j * 16 + col) >= len;
#pragma unroll
        for (int r = 0; r < 4; r++)
          if (inv) sc[j][r] = -3e38f;  // exp2 -> 0
      }
    }

    // ---- static softmax weights: p = exp2(score), f16-rounded for PV ----
#pragma unroll
    for (int r = 0; r < 4; r++) {
#pragma unroll
      for (int j = 0; j < 4; j++) {
        float e = __builtin_exp2f(sc[j][r]);
        QP[p_wr[r][j]] = f2h(e);  // wave-private rows; no barrier needed
        lp[r] += e;               // unrounded sum (mismatch <= 2^-12 rel)
      }
    }

    // ---- O += P * V ----
#pragma unroll
    for (int ks = 0; ks < 2; ks++) {
      half8 pa = *(const half8*)(QP + p_rd[ks]);
#pragma unroll
      for (int j = 0; j < 4; j++) {
        half8 vb = *(const half8*)(cur + 4096 + kvo[ks][j]);
        O[j] = MFMA16(pa, vb, O[j]);
      }
    }

    __syncthreads();  // drain next-tile DMA (overlapped) + sync compute
  }

  // ---- epilogue: reduce l, normalize; per-row override for invalid rows ----
  float l_r[4];
#pragma unroll
  for (int r = 0; r < 4; r++) l_r[r] = rowsum16(lp[r]);
#pragma unroll
  for (int r = 0; r < 4; r++) {
    int s = q0 + w * 16 + quad * 4 + r;
    float invl = 1.0f / l_r[r];
    bool valid = (s < len);
#pragma unroll
    for (int j = 0; j < 4; j++) {
      int d = j * 16 + col;
      float val = valid ? O[j][r] * invl : vsum[bh * 64 + d] * (1.0f / 1024.0f);
      out[(b * 1024 + s) * 1024 + h * 64 + d] = val;
    }
  }
}

// ---------------------------------------------------------------------------
// launch
// ---------------------------------------------------------------------------
extern "C" void kernel_launch(void* const* d_in, const int* in_sizes, int n_in,
                              void* d_out, int out_size, void* d_ws, size_t ws_size,
                              hipStream_t stream) {
  (void)in_sizes; (void)n_in; (void)out_size; (void)ws_size;
  const float* x  = (const float*)d_in[0];
  const float* Wq = (const float*)d_in[1];
  const float* bq = (const float*)d_in[2];
  const float* Wk = (const float*)d_in[3];
  const float* bk = (const float*)d_in[4];
  const float* Wv = (const float*)d_in[5];
  const float* bv = (const float*)d_in[6];
  const int* elen = (const int*)d_in[7];
  float* out = (float*)d_out;

  char* ws = (char*)d_ws;
  const size_t MB = 1024 * 1024;
  u16* xh  = (u16*)(ws + 0 * MB);
  u16* wqT = (u16*)(ws + 8 * MB);
  u16* wkT = (u16*)(ws + 10 * MB);
  u16* wvT = (u16*)(ws + 12 * MB);
  u16* qh  = (u16*)(ws + 14 * MB);
  u16* kh  = (u16*)(ws + 22 * MB);
  u16* vth = (u16*)(ws + 30 * MB);
  float* vsum = (float*)(ws + 38 * MB);  // 4096 floats

  k_prep<<<7168, 256, 0, stream>>>(x, xh, Wq, Wk, Wv, wqT, wkT, wvT, vsum);
  k_proj<<<dim3(32, 8, 3), 256, 0, stream>>>(xh, wqT, wkT, wvT, bq, bk, bv,
                                             qh, kh, vth, vsum);
  k_attn<<<1024, 256, 0, stream>>>(qh, kh, vth, vsum, elen, out);
}